// Round 12
// baseline (1033.396 us; speedup 1.0000x reference)
//
#include <hip/hip_runtime.h>

constexpr int LDIM  = 128;
constexpr int NNODE = 20000;
constexpr int EM_N  = 100000;
constexpr int EW_N  = 25000;
constexpr int NSTEP = 6;

typedef short bf16x8 __attribute__((ext_vector_type(8)));
typedef short bf16x4 __attribute__((ext_vector_type(4)));
typedef float f32x4  __attribute__((ext_vector_type(4)));

struct MlpParams {
  const float* x;
  const float* attrIn;
  float*       attrOut;
  const int*   src;
  const int*   dst;
  const float* gsrc1;   // node: mesh edge attr (gather source)
  const float* gsrc2;   // node: world edge attr
  const int*   off1;    // node: mesh CSR offsets [NNODE+1]
  const int*   csr1;    // node: mesh CSR edge ids
  const int*   off2;
  const int*   csr2;
  const short* W1H;     // bf16 [128 n][384 k]
  const short* W2H;     // bf16 hi [128 n][128 k]
  const short* W2L;     // bf16 lo
  const float* b1;
  const float* b2;
  const float* gam;
  const float* bet;
  int nRows;
};

__device__ __forceinline__ short f2b(float f) {
  unsigned int u = __float_as_uint(f);
  u = (u + 0x7fffu + ((u >> 16) & 1u)) >> 16;
  return (short)u;
}
__device__ __forceinline__ float b2f(short s) {
  return __uint_as_float(((unsigned int)(unsigned short)s) << 16);
}
__device__ __forceinline__ bf16x4 cvt4(float4 a, float sc) {
  bf16x4 o;
  o[0] = f2b(a.x * sc); o[1] = f2b(a.y * sc);
  o[2] = f2b(a.z * sc); o[3] = f2b(a.w * sc);
  return o;
}
__device__ __forceinline__ void add4(float4& a, const float4 b) {
  a.x += b.x; a.y += b.y; a.z += b.z; a.w += b.w;
}

// ================= EDGE kernel: R6 structure VERBATIM, atomics removed =======
// Only delta vs the 126us R6 baseline: no scatter atomicAdds (clean A/B on the
// "16M lane-atomics = ~120us floor" hypothesis).
__launch_bounds__(256, 2)
__global__ void edge_kernel(MlpParams pmA, MlpParams pmB, int blocksA) {
  const bool isA = (int)blockIdx.x < blocksA;
  const MlpParams P = isA ? pmA : pmB;
  const int bid  = isA ? (int)blockIdx.x : (int)blockIdx.x - blocksA;
  const int row0 = bid * 128;

  __shared__ __align__(16) short Abuf[128][40];
  __shared__ __align__(16) short Bhi[128][40];
  __shared__ __align__(16) short Blo[128][40];
  __shared__ __align__(16) short Hbuf[128][136];
  __shared__ float b1s[128], b2s[128], gs[128], bes[128];
  __shared__ int   idxa[128], idxb[128];
  __shared__ float sumL[2][128], sqL[2][128];
  __shared__ float muL[128], rsL[128];

  const int t = threadIdx.x;

  if (t < 128) {
    b1s[t] = P.b1[t];
    gs[t]  = P.gam[t];
    int r = row0 + t;
    idxa[t] = (r < P.nRows) ? P.src[r] : 0;
  } else {
    int t2 = t - 128;
    b2s[t2] = P.b2[t2];
    bes[t2] = P.bet[t2];
    int r = row0 + t2;
    idxb[t2] = (r < P.nRows) ? P.dst[r] : 0;
  }
  __syncthreads();

  const int l   = t & 63;
  const int wid = t >> 6;
  const int wr  = wid >> 1, wcc = wid & 1;
  const int lr  = l & 15,  lg  = l >> 4;

  const int  srow  = t >> 1, sh = t & 1;
  const int  sgRow = row0 + srow;
  const bool sval  = sgRow < P.nRows;
  const int  sgC   = sval ? sgRow : 0;
  const float vmask = sval ? 1.f : 0.f;

  const float* base0 = P.x + (size_t)idxa[srow] * LDIM + sh * 16;
  const float* base1 = P.x + (size_t)idxb[srow] * LDIM + sh * 16;
  const float* base2 = P.attrIn + (size_t)sgC * LDIM + sh * 16;

  const int wrow = t >> 1, wsh = t & 1;
  const short* w1base = P.W1H + (size_t)wrow * 384 + wsh * 16;

  f32x4 acc[4][4];
#pragma unroll
  for (int i = 0; i < 4; ++i)
#pragma unroll
    for (int j = 0; j < 4; ++j) acc[i][j] = f32x4{0.f, 0.f, 0.f, 0.f};

  float4 pA0, pA1, pA2, pA3;
  bf16x8 pW0, pW1;
  {
    const float4* bp = (const float4*)base0;
    pA0 = bp[0]; pA1 = bp[1]; pA2 = bp[2]; pA3 = bp[3];
    pW0 = *(const bf16x8*)w1base;
    pW1 = *(const bf16x8*)(w1base + 8);
  }

  // phase 1
#pragma unroll
  for (int kc = 0; kc < 12; ++kc) {
    if (kc > 0) __syncthreads();
    {
      *(bf16x4*)&Abuf[srow][sh * 16 + 0]  = cvt4(pA0, vmask);
      *(bf16x4*)&Abuf[srow][sh * 16 + 4]  = cvt4(pA1, vmask);
      *(bf16x4*)&Abuf[srow][sh * 16 + 8]  = cvt4(pA2, vmask);
      *(bf16x4*)&Abuf[srow][sh * 16 + 12] = cvt4(pA3, vmask);
      *(bf16x8*)&Bhi[wrow][wsh * 16]     = pW0;
      *(bf16x8*)&Bhi[wrow][wsh * 16 + 8] = pW1;
    }
    __syncthreads();
    if (kc < 11) {
      const int kn = kc + 1, segn = kn >> 2, partn = kn & 3;
      const float4* bp = (const float4*)((segn == 0 ? base0 : segn == 1 ? base1 : base2) + partn * 32);
      pA0 = bp[0]; pA1 = bp[1]; pA2 = bp[2]; pA3 = bp[3];
      pW0 = *(const bf16x8*)(w1base + kn * 32);
      pW1 = *(const bf16x8*)(w1base + kn * 32 + 8);
    }
    bf16x8 av[4], bh[4];
#pragma unroll
    for (int mi = 0; mi < 4; ++mi)
      av[mi] = *(const bf16x8*)&Abuf[wr * 64 + mi * 16 + lr][lg * 8];
#pragma unroll
    for (int ni = 0; ni < 4; ++ni)
      bh[ni] = *(const bf16x8*)&Bhi[wcc * 64 + ni * 16 + lr][lg * 8];
#pragma unroll
    for (int mi = 0; mi < 4; ++mi)
#pragma unroll
      for (int ni = 0; ni < 4; ++ni)
        acc[mi][ni] = __builtin_amdgcn_mfma_f32_16x16x32_bf16(av[mi], bh[ni], acc[mi][ni], 0, 0, 0);
  }

  // H write (acc dies)
#pragma unroll
  for (int rt = 0; rt < 4; ++rt)
#pragma unroll
    for (int ct = 0; ct < 4; ++ct) {
      const int cc = wcc * 64 + ct * 16 + lr;
      const float bb = b1s[cc];
#pragma unroll
      for (int q = 0; q < 4; ++q) {
        const int rr = wr * 64 + rt * 16 + lg * 4 + q;
        Hbuf[rr][cc] = f2b(fmaxf(acc[rt][ct][q] + bb, 0.f));
      }
    }

  // phase 2 (W2 hi/lo, prefetched)
  f32x4 acc2[4][4];
#pragma unroll
  for (int i = 0; i < 4; ++i)
#pragma unroll
    for (int j = 0; j < 4; ++j) acc2[i][j] = f32x4{0.f, 0.f, 0.f, 0.f};

  const short* w2hbase = P.W2H + (size_t)wrow * 128 + wsh * 16;
  const short* w2lbase = P.W2L + (size_t)wrow * 128 + wsh * 16;

  bf16x8 qh0 = *(const bf16x8*)w2hbase;
  bf16x8 qh1 = *(const bf16x8*)(w2hbase + 8);
  bf16x8 ql0 = *(const bf16x8*)w2lbase;
  bf16x8 ql1 = *(const bf16x8*)(w2lbase + 8);

#pragma unroll
  for (int kc = 0; kc < 4; ++kc) {
    __syncthreads();
    {
      *(bf16x8*)&Bhi[wrow][wsh * 16]     = qh0;
      *(bf16x8*)&Bhi[wrow][wsh * 16 + 8] = qh1;
      *(bf16x8*)&Blo[wrow][wsh * 16]     = ql0;
      *(bf16x8*)&Blo[wrow][wsh * 16 + 8] = ql1;
    }
    __syncthreads();
    if (kc < 3) {
      qh0 = *(const bf16x8*)(w2hbase + (kc + 1) * 32);
      qh1 = *(const bf16x8*)(w2hbase + (kc + 1) * 32 + 8);
      ql0 = *(const bf16x8*)(w2lbase + (kc + 1) * 32);
      ql1 = *(const bf16x8*)(w2lbase + (kc + 1) * 32 + 8);
    }
    bf16x8 av2[4], bh2[4], bl2[4];
#pragma unroll
    for (int rt = 0; rt < 4; ++rt)
      av2[rt] = *(const bf16x8*)&Hbuf[wr * 64 + rt * 16 + lr][kc * 32 + lg * 8];
#pragma unroll
    for (int ct = 0; ct < 4; ++ct) {
      bh2[ct] = *(const bf16x8*)&Bhi[wcc * 64 + ct * 16 + lr][lg * 8];
      bl2[ct] = *(const bf16x8*)&Blo[wcc * 64 + ct * 16 + lr][lg * 8];
    }
#pragma unroll
    for (int rt = 0; rt < 4; ++rt)
#pragma unroll
      for (int ct = 0; ct < 4; ++ct) {
        acc2[rt][ct] = __builtin_amdgcn_mfma_f32_16x16x32_bf16(av2[rt], bl2[ct], acc2[rt][ct], 0, 0, 0);
        acc2[rt][ct] = __builtin_amdgcn_mfma_f32_16x16x32_bf16(av2[rt], bh2[ct], acc2[rt][ct], 0, 0, 0);
      }
  }

  // epilogue (NO atomics)
  float s1[4][4], s2[4][4];
#pragma unroll
  for (int rt = 0; rt < 4; ++rt)
#pragma unroll
    for (int q = 0; q < 4; ++q) { s1[rt][q] = 0.f; s2[rt][q] = 0.f; }
#pragma unroll
  for (int rt = 0; rt < 4; ++rt)
#pragma unroll
    for (int ct = 0; ct < 4; ++ct) {
      const float bb = b2s[wcc * 64 + ct * 16 + lr];
#pragma unroll
      for (int q = 0; q < 4; ++q) {
        float v = acc2[rt][ct][q] + bb;
        acc2[rt][ct][q] = v;
        s1[rt][q] += v;
        s2[rt][q] += v * v;
      }
    }
#pragma unroll
  for (int m = 1; m < 16; m <<= 1) {
#pragma unroll
    for (int rt = 0; rt < 4; ++rt)
#pragma unroll
      for (int q = 0; q < 4; ++q) {
        s1[rt][q] += __shfl_xor(s1[rt][q], m);
        s2[rt][q] += __shfl_xor(s2[rt][q], m);
      }
  }
  __syncthreads();
  {
    const int rt = lr >> 2, q = lr & 3;
    const int rr = wr * 64 + rt * 16 + lg * 4 + q;
    sumL[wcc][rr] = s1[rt][q];
    sqL[wcc][rr]  = s2[rt][q];
  }
  __syncthreads();
  if (t < 128) {
    const float tot = sumL[0][t] + sumL[1][t];
    const float tsq = sqL[0][t] + sqL[1][t];
    const float mu  = tot * (1.0f / 128.0f);
    const float var = tsq * (1.0f / 128.0f) - mu * mu;
    muL[t] = mu;
    rsL[t] = rsqrtf(var + 1e-5f);
  }
  __syncthreads();

#pragma unroll
  for (int rt = 0; rt < 4; ++rt) {
#pragma unroll
    for (int q = 0; q < 4; ++q) {
      const int rr = wr * 64 + rt * 16 + lg * 4 + q;
      const int grow = row0 + rr;
      if (grow < P.nRows) {
        const float mu = muL[rr], rs = rsL[rr];
        const float* rin = P.attrIn + (size_t)grow * LDIM;
        float* rout = P.attrOut + (size_t)grow * LDIM;
#pragma unroll
        for (int ct = 0; ct < 4; ++ct) {
          const int cc = wcc * 64 + ct * 16 + lr;
          rout[cc] = gs[cc] * (acc2[rt][ct][q] - mu) * rs + bes[cc] + rin[cc];
        }
      }
    }
  }
}

// ================= NODE kernel: CSR gather-mean aggregation ==================
__launch_bounds__(256, 2)
__global__ void node_kernel(MlpParams P) {
  const int bid  = (int)blockIdx.x;
  const int row0 = bid * 128;

  __shared__ __align__(16) short Abuf[128][40];
  __shared__ __align__(16) short Bhi[128][40];
  __shared__ __align__(16) short Blo[128][40];
  __shared__ __align__(16) short Hbuf[128][136];
  __shared__ float b1s[128], b2s[128], gs[128], bes[128];
  __shared__ float sumL[2][128], sqL[2][128];
  __shared__ float muL[128], rsL[128];

  const int t = threadIdx.x;
  if (t < 128) { b1s[t] = P.b1[t]; gs[t] = P.gam[t]; }
  else         { b2s[t - 128] = P.b2[t - 128]; bes[t - 128] = P.bet[t - 128]; }

  const int l   = t & 63;
  const int wid = t >> 6;
  const int wr  = wid >> 1, wcc = wid & 1;
  const int lr  = l & 15,  lg  = l >> 4;

  const int  srow  = t >> 1, sh = t & 1;
  const int  sgRow = row0 + srow;
  const bool sval  = sgRow < P.nRows;

  const int wrow = t >> 1, wsh = t & 1;
  const short* w1base = P.W1H + (size_t)wrow * 384 + wsh * 16;

  f32x4 acc[4][4];
#pragma unroll
  for (int i = 0; i < 4; ++i)
#pragma unroll
    for (int j = 0; j < 4; ++j) acc[i][j] = f32x4{0.f, 0.f, 0.f, 0.f};

  __syncthreads();   // b1s etc ready

  // phase 1: staging inline (seg0 = x copy; seg1/2 = CSR gather-mean)
#pragma unroll
  for (int kc = 0; kc < 12; ++kc) {
    const int seg = kc >> 2, part = kc & 3;
    if (kc > 0) __syncthreads();
    {
      float4 s0{0,0,0,0}, s1{0,0,0,0}, s2{0,0,0,0}, s3{0,0,0,0};
      float sc = 1.f;
      if (seg == 0) {
        if (sval) {
          const float4* p = (const float4*)(P.x + (size_t)sgRow * LDIM + part * 32 + sh * 16);
          s0 = p[0]; s1 = p[1]; s2 = p[2]; s3 = p[3];
        }
      } else {
        const int* off = (seg == 1) ? P.off1 : P.off2;
        const int* csr = (seg == 1) ? P.csr1 : P.csr2;
        const float* src = (seg == 1) ? P.gsrc1 : P.gsrc2;
        int beg = 0, end = 0;
        if (sval) { beg = off[sgRow]; end = off[sgRow + 1]; }
        for (int i = beg; i < end; ++i) {
          const float4* p = (const float4*)(src + (size_t)csr[i] * LDIM + part * 32 + sh * 16);
          add4(s0, p[0]); add4(s1, p[1]); add4(s2, p[2]); add4(s3, p[3]);
        }
        sc = 1.0f / (float)max(end - beg, 1);
      }
      *(bf16x4*)&Abuf[srow][sh * 16 + 0]  = cvt4(s0, sc);
      *(bf16x4*)&Abuf[srow][sh * 16 + 4]  = cvt4(s1, sc);
      *(bf16x4*)&Abuf[srow][sh * 16 + 8]  = cvt4(s2, sc);
      *(bf16x4*)&Abuf[srow][sh * 16 + 12] = cvt4(s3, sc);
      const short* wsrc = w1base + kc * 32;
      *(bf16x8*)&Bhi[wrow][wsh * 16]     = *(const bf16x8*)wsrc;
      *(bf16x8*)&Bhi[wrow][wsh * 16 + 8] = *(const bf16x8*)(wsrc + 8);
    }
    __syncthreads();
    bf16x8 av[4], bh[4];
#pragma unroll
    for (int mi = 0; mi < 4; ++mi)
      av[mi] = *(const bf16x8*)&Abuf[wr * 64 + mi * 16 + lr][lg * 8];
#pragma unroll
    for (int ni = 0; ni < 4; ++ni)
      bh[ni] = *(const bf16x8*)&Bhi[wcc * 64 + ni * 16 + lr][lg * 8];
#pragma unroll
    for (int mi = 0; mi < 4; ++mi)
#pragma unroll
      for (int ni = 0; ni < 4; ++ni)
        acc[mi][ni] = __builtin_amdgcn_mfma_f32_16x16x32_bf16(av[mi], bh[ni], acc[mi][ni], 0, 0, 0);
  }

  // H write (acc dies)
#pragma unroll
  for (int rt = 0; rt < 4; ++rt)
#pragma unroll
    for (int ct = 0; ct < 4; ++ct) {
      const int cc = wcc * 64 + ct * 16 + lr;
      const float bb = b1s[cc];
#pragma unroll
      for (int q = 0; q < 4; ++q) {
        const int rr = wr * 64 + rt * 16 + lg * 4 + q;
        Hbuf[rr][cc] = f2b(fmaxf(acc[rt][ct][q] + bb, 0.f));
      }
    }

  // phase 2 (W2 hi/lo)
  f32x4 acc2[4][4];
#pragma unroll
  for (int i = 0; i < 4; ++i)
#pragma unroll
    for (int j = 0; j < 4; ++j) acc2[i][j] = f32x4{0.f, 0.f, 0.f, 0.f};

  const short* w2hbase = P.W2H + (size_t)wrow * 128 + wsh * 16;
  const short* w2lbase = P.W2L + (size_t)wrow * 128 + wsh * 16;
  bf16x8 qh0 = *(const bf16x8*)w2hbase;
  bf16x8 qh1 = *(const bf16x8*)(w2hbase + 8);
  bf16x8 ql0 = *(const bf16x8*)w2lbase;
  bf16x8 ql1 = *(const bf16x8*)(w2lbase + 8);

#pragma unroll
  for (int kc = 0; kc < 4; ++kc) {
    __syncthreads();
    {
      *(bf16x8*)&Bhi[wrow][wsh * 16]     = qh0;
      *(bf16x8*)&Bhi[wrow][wsh * 16 + 8] = qh1;
      *(bf16x8*)&Blo[wrow][wsh * 16]     = ql0;
      *(bf16x8*)&Blo[wrow][wsh * 16 + 8] = ql1;
    }
    __syncthreads();
    if (kc < 3) {
      qh0 = *(const bf16x8*)(w2hbase + (kc + 1) * 32);
      qh1 = *(const bf16x8*)(w2hbase + (kc + 1) * 32 + 8);
      ql0 = *(const bf16x8*)(w2lbase + (kc + 1) * 32);
      ql1 = *(const bf16x8*)(w2lbase + (kc + 1) * 32 + 8);
    }
    bf16x8 av2[4], bh2[4], bl2[4];
#pragma unroll
    for (int rt = 0; rt < 4; ++rt)
      av2[rt] = *(const bf16x8*)&Hbuf[wr * 64 + rt * 16 + lr][kc * 32 + lg * 8];
#pragma unroll
    for (int ct = 0; ct < 4; ++ct) {
      bh2[ct] = *(const bf16x8*)&Bhi[wcc * 64 + ct * 16 + lr][lg * 8];
      bl2[ct] = *(const bf16x8*)&Blo[wcc * 64 + ct * 16 + lr][lg * 8];
    }
#pragma unroll
    for (int rt = 0; rt < 4; ++rt)
#pragma unroll
      for (int ct = 0; ct < 4; ++ct) {
        acc2[rt][ct] = __builtin_amdgcn_mfma_f32_16x16x32_bf16(av2[rt], bl2[ct], acc2[rt][ct], 0, 0, 0);
        acc2[rt][ct] = __builtin_amdgcn_mfma_f32_16x16x32_bf16(av2[rt], bh2[ct], acc2[rt][ct], 0, 0, 0);
      }
  }

  // epilogue
  float s1[4][4], s2[4][4];
#pragma unroll
  for (int rt = 0; rt < 4; ++rt)
#pragma unroll
    for (int q = 0; q < 4; ++q) { s1[rt][q] = 0.f; s2[rt][q] = 0.f; }
#pragma unroll
  for (int rt = 0; rt < 4; ++rt)
#pragma unroll
    for (int ct = 0; ct < 4; ++ct) {
      const float bb = b2s[wcc * 64 + ct * 16 + lr];
#pragma unroll
      for (int q = 0; q < 4; ++q) {
        float v = acc2[rt][ct][q] + bb;
        acc2[rt][ct][q] = v;
        s1[rt][q] += v;
        s2[rt][q] += v * v;
      }
    }
#pragma unroll
  for (int m = 1; m < 16; m <<= 1) {
#pragma unroll
    for (int rt = 0; rt < 4; ++rt)
#pragma unroll
      for (int q = 0; q < 4; ++q) {
        s1[rt][q] += __shfl_xor(s1[rt][q], m);
        s2[rt][q] += __shfl_xor(s2[rt][q], m);
      }
  }
  __syncthreads();
  {
    const int rt = lr >> 2, q = lr & 3;
    const int rr = wr * 64 + rt * 16 + lg * 4 + q;
    sumL[wcc][rr] = s1[rt][q];
    sqL[wcc][rr]  = s2[rt][q];
  }
  __syncthreads();
  if (t < 128) {
    const float tot = sumL[0][t] + sumL[1][t];
    const float tsq = sqL[0][t] + sqL[1][t];
    const float mu  = tot * (1.0f / 128.0f);
    const float var = tsq * (1.0f / 128.0f) - mu * mu;
    muL[t] = mu;
    rsL[t] = rsqrtf(var + 1e-5f);
  }
  __syncthreads();

#pragma unroll
  for (int rt = 0; rt < 4; ++rt) {
#pragma unroll
    for (int q = 0; q < 4; ++q) {
      const int rr = wr * 64 + rt * 16 + lg * 4 + q;
      const int grow = row0 + rr;
      if (grow < P.nRows) {
        const float mu = muL[rr], rs = rsL[rr];
        const float* rin = P.attrIn + (size_t)grow * LDIM;
        float* rout = P.attrOut + (size_t)grow * LDIM;
#pragma unroll
        for (int ct = 0; ct < 4; ++ct) {
          const int cc = wcc * 64 + ct * 16 + lr;
          rout[cc] = gs[cc] * (acc2[rt][ct][q] - mu) * rs + bes[cc] + rin[cc];
        }
      }
    }
  }
}

// ---- prep kernels ----
__global__ void prep_weights(const float* w1a, const float* w1b, const float* w1c,
                             const float* w2a, const float* w2b, const float* w2c,
                             short* w1h, short* w2h, short* w2l) {
  int i = blockIdx.x * 256 + threadIdx.x;
  constexpr int N1 = 18 * 128 * 384;
  constexpr int N2 = 18 * 128 * 128;
  if (i < N1) {
    int g = i / (128 * 384);
    int rem = i - g * (128 * 384);
    int n = rem / 384, k = rem - n * 384;
    int m = g / 6, s = g - m * 6;
    const float* src = (m == 0) ? w1a : (m == 1) ? w1b : w1c;
    w1h[i] = f2b(src[(size_t)s * (384 * 128) + (size_t)k * 128 + n]);
  } else if (i < N1 + N2) {
    int j = i - N1;
    int g = j / (128 * 128);
    int rem = j - g * (128 * 128);
    int n = rem / 128, k = rem - n * 128;
    int m = g / 6, s = g - m * 6;
    const float* src = (m == 0) ? w2a : (m == 1) ? w2b : w2c;
    float f = src[(size_t)s * (128 * 128) + (size_t)k * 128 + n];
    short hi = f2b(f);
    w2h[j] = hi;
    w2l[j] = f2b(f - b2f(hi));
  }
}

__global__ void prep_deg(const int* mr, const int* wrcv, int* degm, int* degw) {
  int i = blockIdx.x * 256 + threadIdx.x;
  if (i < EM_N) atomicAdd(&degm[mr[i]], 1);
  else if (i < EM_N + EW_N) atomicAdd(&degw[wrcv[i - EM_N]], 1);
}

// single-block exclusive scan: degm->moff, degw->woff
__global__ void prep_scan(const int* degm, const int* degw, int* moff, int* woff) {
  __shared__ int part[256];
  const int t = threadIdx.x;
  constexpr int NPT = (NNODE + 255) / 256;   // 79
#pragma unroll 1
  for (int pass = 0; pass < 2; ++pass) {
    const int* deg = pass == 0 ? degm : degw;
    int* off = pass == 0 ? moff : woff;
    int s = 0;
    for (int i = 0; i < NPT; ++i) {
      int n = t * NPT + i;
      if (n < NNODE) s += deg[n];
    }
    part[t] = s;
    __syncthreads();
    for (int d = 1; d < 256; d <<= 1) {
      int v = (t >= d) ? part[t - d] : 0;
      __syncthreads();
      part[t] += v;
      __syncthreads();
    }
    int base = (t == 0) ? 0 : part[t - 1];
    for (int i = 0; i < NPT; ++i) {
      int n = t * NPT + i;
      if (n < NNODE) { off[n] = base; base += deg[n]; }
    }
    if (t == 255) off[NNODE] = base;
    __syncthreads();
  }
}

__global__ void prep_fill(const int* mr, const int* wrcv,
                          const int* moff, const int* woff,
                          int* mcur, int* wcur, int* mcsr, int* wcsr) {
  int i = blockIdx.x * 256 + threadIdx.x;
  if (i < EM_N) {
    int d = mr[i];
    int pos = moff[d] + atomicAdd(&mcur[d], 1);
    mcsr[pos] = i;
  } else if (i < EM_N + EW_N) {
    int j = i - EM_N;
    int d = wrcv[j];
    int pos = woff[d] + atomicAdd(&wcur[d], 1);
    wcsr[pos] = j;
  }
}

extern "C" void kernel_launch(void* const* d_in, const int* in_sizes, int n_in,
                              void* d_out, int out_size, void* d_ws, size_t ws_size,
                              hipStream_t stream) {
  (void)in_sizes; (void)n_in; (void)out_size; (void)ws_size;
  const float* x_in   = (const float*)d_in[0];
  const float* mea_in = (const float*)d_in[1];
  const float* wea_in = (const float*)d_in[2];
  const int*   mei    = (const int*)d_in[3];
  const int*   wei    = (const int*)d_in[4];
  const float* W1s[3] = { (const float*)d_in[5],  (const float*)d_in[11], (const float*)d_in[17] };
  const float* B1s[3] = { (const float*)d_in[6],  (const float*)d_in[12], (const float*)d_in[18] };
  const float* W2s[3] = { (const float*)d_in[7],  (const float*)d_in[13], (const float*)d_in[19] };
  const float* B2s[3] = { (const float*)d_in[8],  (const float*)d_in[14], (const float*)d_in[20] };
  const float* Gs[3]  = { (const float*)d_in[9],  (const float*)d_in[15], (const float*)d_in[21] };
  const float* Be[3]  = { (const float*)d_in[10], (const float*)d_in[16], (const float*)d_in[22] };

  float* xo  = (float*)d_out;
  float* meo = xo  + (size_t)NNODE * LDIM;
  float* weo = meo + (size_t)EM_N * LDIM;

  int*   degm = (int*)d_ws;
  int*   degw = degm + NNODE;
  int*   mcur = degw + NNODE;
  int*   wcur = mcur + NNODE;
  int*   moff = wcur + NNODE;
  int*   woff = moff + (NNODE + 1);
  int*   mcsr = woff + (NNODE + 1);
  int*   wcsr = mcsr + EM_N;
  short* w1h  = (short*)(wcsr + EW_N);
  short* w2h  = w1h + (size_t)18 * 128 * 384;
  short* w2l  = w2h + (size_t)18 * 128 * 128;

  hipMemsetAsync(d_ws, 0, (size_t)4 * NNODE * 4, stream);  // degm,degw,mcur,wcur

  {
    int tot = 18 * 128 * 384 + 18 * 128 * 128;
    prep_weights<<<dim3((tot + 255) / 256), 256, 0, stream>>>(
        W1s[0], W1s[1], W1s[2], W2s[0], W2s[1], W2s[2], w1h, w2h, w2l);
  }
  prep_deg<<<dim3((EM_N + EW_N + 255) / 256), 256, 0, stream>>>(mei + EM_N, wei + EW_N, degm, degw);
  prep_scan<<<dim3(1), 256, 0, stream>>>(degm, degw, moff, woff);
  prep_fill<<<dim3((EM_N + EW_N + 255) / 256), 256, 0, stream>>>(
      mei + EM_N, wei + EW_N, moff, woff, mcur, wcur, mcsr, wcsr);

  const int MB = (EM_N + 127) / 128;   // 782
  const int WB = (EW_N + 127) / 128;   // 196
  const int NB = (NNODE + 127) / 128;  // 157

  const float* xc = x_in;
  const float* mc = mea_in;
  const float* wc = wea_in;

  for (int s = 0; s < NSTEP; ++s) {
    MlpParams pm{}, pw{}, pn{};

    pm.x = xc; pm.attrIn = mc; pm.attrOut = meo;
    pm.src = mei; pm.dst = mei + EM_N;
    pm.W1H = w1h + (size_t)(0 * 6 + s) * 128 * 384;
    pm.W2H = w2h + (size_t)(0 * 6 + s) * 128 * 128;
    pm.W2L = w2l + (size_t)(0 * 6 + s) * 128 * 128;
    pm.b1 = B1s[0] + s * LDIM; pm.b2 = B2s[0] + s * LDIM;
    pm.gam = Gs[0] + s * LDIM; pm.bet = Be[0] + s * LDIM;
    pm.nRows = EM_N;

    pw.x = xc; pw.attrIn = wc; pw.attrOut = weo;
    pw.src = wei; pw.dst = wei + EW_N;
    pw.W1H = w1h + (size_t)(1 * 6 + s) * 128 * 384;
    pw.W2H = w2h + (size_t)(1 * 6 + s) * 128 * 128;
    pw.W2L = w2l + (size_t)(1 * 6 + s) * 128 * 128;
    pw.b1 = B1s[1] + s * LDIM; pw.b2 = B2s[1] + s * LDIM;
    pw.gam = Gs[1] + s * LDIM; pw.bet = Be[1] + s * LDIM;
    pw.nRows = EW_N;

    edge_kernel<<<dim3(MB + WB), 256, 0, stream>>>(pm, pw, MB);

    pn.x = xc; pn.attrIn = xc; pn.attrOut = xo;
    pn.gsrc1 = meo; pn.gsrc2 = weo;
    pn.off1 = moff; pn.csr1 = mcsr;
    pn.off2 = woff; pn.csr2 = wcsr;
    pn.W1H = w1h + (size_t)(2 * 6 + s) * 128 * 384;
    pn.W2H = w2h + (size_t)(2 * 6 + s) * 128 * 128;
    pn.W2L = w2l + (size_t)(2 * 6 + s) * 128 * 128;
    pn.b1 = B1s[2] + s * LDIM; pn.b2 = B2s[2] + s * LDIM;
    pn.gam = Gs[2] + s * LDIM; pn.bet = Be[2] + s * LDIM;
    pn.nRows = NNODE;

    node_kernel<<<dim3(NB), 256, 0, stream>>>(pn);

    xc = xo; mc = meo; wc = weo;
  }
}

// Round 13
// 890.981 us; speedup vs baseline: 1.1598x; 1.1598x over previous
//
#include <hip/hip_runtime.h>

constexpr int LDIM  = 128;
constexpr int NNODE = 20000;
constexpr int EM_N  = 100000;
constexpr int EW_N  = 25000;
constexpr int NSTEP = 6;

typedef short bf16x8 __attribute__((ext_vector_type(8)));
typedef short bf16x4 __attribute__((ext_vector_type(4)));
typedef float f32x4  __attribute__((ext_vector_type(4)));

struct MlpParams {
  const short* xb;      // bf16 node features (gather source)
  const float* attrIn;  // residual input (f32)
  float*       attrOut;
  short*       xbOut;   // node: bf16 copy of new x
  const int*   src;
  const int*   dst;
  const float* gsrc1;   // node: mesh edge attr (gather source)
  const float* gsrc2;   // node: world edge attr
  const int*   off1;    // node: mesh CSR offsets [NNODE+1]
  const int*   csr1;    // node: mesh CSR edge ids
  const int*   off2;
  const int*   csr2;
  const short* W1H;     // bf16 [128 n][384 k]
  const short* W2H;     // bf16 hi [128 n][128 k]
  const short* W2L;     // bf16 lo
  const float* b1;
  const float* b2;
  const float* gam;
  const float* bet;
  int nRows;
};

__device__ __forceinline__ short f2b(float f) {
  unsigned int u = __float_as_uint(f);
  u = (u + 0x7fffu + ((u >> 16) & 1u)) >> 16;
  return (short)u;
}
__device__ __forceinline__ float b2f(short s) {
  return __uint_as_float(((unsigned int)(unsigned short)s) << 16);
}
__device__ __forceinline__ bf16x4 cvt4(float4 a, float sc) {
  bf16x4 o;
  o[0] = f2b(a.x * sc); o[1] = f2b(a.y * sc);
  o[2] = f2b(a.z * sc); o[3] = f2b(a.w * sc);
  return o;
}
__device__ __forceinline__ bf16x4 cvt4v(f32x4 a, float sc) {
  bf16x4 o;
  o[0] = f2b(a[0] * sc); o[1] = f2b(a[1] * sc);
  o[2] = f2b(a[2] * sc); o[3] = f2b(a[3] * sc);
  return o;
}

// ================= EDGE kernel: R12 structure, x gathers now bf16 ===========
__launch_bounds__(256, 2)
__global__ void edge_kernel(MlpParams pmA, MlpParams pmB, int blocksA) {
  const bool isA = (int)blockIdx.x < blocksA;
  const MlpParams P = isA ? pmA : pmB;
  const int bid  = isA ? (int)blockIdx.x : (int)blockIdx.x - blocksA;
  const int row0 = bid * 128;

  __shared__ __align__(16) short Abuf[128][40];
  __shared__ __align__(16) short Bhi[128][40];
  __shared__ __align__(16) short Blo[128][40];
  __shared__ __align__(16) short Hbuf[128][136];
  __shared__ float b1s[128], b2s[128], gs[128], bes[128];
  __shared__ int   idxa[128], idxb[128];
  __shared__ float sumL[2][128], sqL[2][128];
  __shared__ float muL[128], rsL[128];

  const int t = threadIdx.x;

  if (t < 128) {
    b1s[t] = P.b1[t];
    gs[t]  = P.gam[t];
    int r = row0 + t;
    idxa[t] = (r < P.nRows) ? P.src[r] : 0;
  } else {
    int t2 = t - 128;
    b2s[t2] = P.b2[t2];
    bes[t2] = P.bet[t2];
    int r = row0 + t2;
    idxb[t2] = (r < P.nRows) ? P.dst[r] : 0;
  }
  __syncthreads();

  const int l   = t & 63;
  const int wid = t >> 6;
  const int wr  = wid >> 1, wcc = wid & 1;
  const int lr  = l & 15,  lg  = l >> 4;

  const int  srow  = t >> 1, sh = t & 1;
  const int  sgRow = row0 + srow;
  const bool sval  = sgRow < P.nRows;
  const int  sgC   = sval ? sgRow : 0;
  const float vmask = sval ? 1.f : 0.f;

  const short* bx0   = P.xb + (size_t)idxa[srow] * LDIM + sh * 16;
  const short* bx1   = P.xb + (size_t)idxb[srow] * LDIM + sh * 16;
  const float* base2 = P.attrIn + (size_t)sgC * LDIM + sh * 16;

  const int wrow = t >> 1, wsh = t & 1;
  const short* w1base = P.W1H + (size_t)wrow * 384 + wsh * 16;

  f32x4 acc[4][4];
#pragma unroll
  for (int i = 0; i < 4; ++i)
#pragma unroll
    for (int j = 0; j < 4; ++j) acc[i][j] = f32x4{0.f, 0.f, 0.f, 0.f};

  const bf16x8 z8 = {0, 0, 0, 0, 0, 0, 0, 0};
  bf16x8 pB0, pB1;          // seg0/seg1 prefetch (bf16)
  float4 pA0, pA1, pA2, pA3; // seg2 prefetch (f32)
  bf16x8 pW0, pW1;
  {
    pB0 = *(const bf16x8*)bx0;
    pB1 = *(const bf16x8*)(bx0 + 8);
    pW0 = *(const bf16x8*)w1base;
    pW1 = *(const bf16x8*)(w1base + 8);
  }

  // phase 1
#pragma unroll
  for (int kc = 0; kc < 12; ++kc) {
    const int seg = kc >> 2;
    if (kc > 0) __syncthreads();
    {
      if (seg < 2) {
        *(bf16x8*)&Abuf[srow][sh * 16]     = sval ? pB0 : z8;
        *(bf16x8*)&Abuf[srow][sh * 16 + 8] = sval ? pB1 : z8;
      } else {
        *(bf16x4*)&Abuf[srow][sh * 16 + 0]  = cvt4(pA0, vmask);
        *(bf16x4*)&Abuf[srow][sh * 16 + 4]  = cvt4(pA1, vmask);
        *(bf16x4*)&Abuf[srow][sh * 16 + 8]  = cvt4(pA2, vmask);
        *(bf16x4*)&Abuf[srow][sh * 16 + 12] = cvt4(pA3, vmask);
      }
      *(bf16x8*)&Bhi[wrow][wsh * 16]     = pW0;
      *(bf16x8*)&Bhi[wrow][wsh * 16 + 8] = pW1;
    }
    __syncthreads();
    if (kc < 11) {
      const int kn = kc + 1, segn = kn >> 2, partn = kn & 3;
      if (segn == 0) {
        pB0 = *(const bf16x8*)(bx0 + partn * 32);
        pB1 = *(const bf16x8*)(bx0 + partn * 32 + 8);
      } else if (segn == 1) {
        pB0 = *(const bf16x8*)(bx1 + partn * 32);
        pB1 = *(const bf16x8*)(bx1 + partn * 32 + 8);
      } else {
        const float4* bp = (const float4*)(base2 + partn * 32);
        pA0 = bp[0]; pA1 = bp[1]; pA2 = bp[2]; pA3 = bp[3];
      }
      pW0 = *(const bf16x8*)(w1base + kn * 32);
      pW1 = *(const bf16x8*)(w1base + kn * 32 + 8);
    }
    bf16x8 av[4], bh[4];
#pragma unroll
    for (int mi = 0; mi < 4; ++mi)
      av[mi] = *(const bf16x8*)&Abuf[wr * 64 + mi * 16 + lr][lg * 8];
#pragma unroll
    for (int ni = 0; ni < 4; ++ni)
      bh[ni] = *(const bf16x8*)&Bhi[wcc * 64 + ni * 16 + lr][lg * 8];
#pragma unroll
    for (int mi = 0; mi < 4; ++mi)
#pragma unroll
      for (int ni = 0; ni < 4; ++ni)
        acc[mi][ni] = __builtin_amdgcn_mfma_f32_16x16x32_bf16(av[mi], bh[ni], acc[mi][ni], 0, 0, 0);
  }

  // H write (acc dies)
#pragma unroll
  for (int rt = 0; rt < 4; ++rt)
#pragma unroll
    for (int ct = 0; ct < 4; ++ct) {
      const int cc = wcc * 64 + ct * 16 + lr;
      const float bb = b1s[cc];
#pragma unroll
      for (int q = 0; q < 4; ++q) {
        const int rr = wr * 64 + rt * 16 + lg * 4 + q;
        Hbuf[rr][cc] = f2b(fmaxf(acc[rt][ct][q] + bb, 0.f));
      }
    }

  // phase 2 (W2 hi/lo, prefetched)
  f32x4 acc2[4][4];
#pragma unroll
  for (int i = 0; i < 4; ++i)
#pragma unroll
    for (int j = 0; j < 4; ++j) acc2[i][j] = f32x4{0.f, 0.f, 0.f, 0.f};

  const short* w2hbase = P.W2H + (size_t)wrow * 128 + wsh * 16;
  const short* w2lbase = P.W2L + (size_t)wrow * 128 + wsh * 16;

  bf16x8 qh0 = *(const bf16x8*)w2hbase;
  bf16x8 qh1 = *(const bf16x8*)(w2hbase + 8);
  bf16x8 ql0 = *(const bf16x8*)w2lbase;
  bf16x8 ql1 = *(const bf16x8*)(w2lbase + 8);

#pragma unroll
  for (int kc = 0; kc < 4; ++kc) {
    __syncthreads();
    {
      *(bf16x8*)&Bhi[wrow][wsh * 16]     = qh0;
      *(bf16x8*)&Bhi[wrow][wsh * 16 + 8] = qh1;
      *(bf16x8*)&Blo[wrow][wsh * 16]     = ql0;
      *(bf16x8*)&Blo[wrow][wsh * 16 + 8] = ql1;
    }
    __syncthreads();
    if (kc < 3) {
      qh0 = *(const bf16x8*)(w2hbase + (kc + 1) * 32);
      qh1 = *(const bf16x8*)(w2hbase + (kc + 1) * 32 + 8);
      ql0 = *(const bf16x8*)(w2lbase + (kc + 1) * 32);
      ql1 = *(const bf16x8*)(w2lbase + (kc + 1) * 32 + 8);
    }
    bf16x8 av2[4], bh2[4], bl2[4];
#pragma unroll
    for (int rt = 0; rt < 4; ++rt)
      av2[rt] = *(const bf16x8*)&Hbuf[wr * 64 + rt * 16 + lr][kc * 32 + lg * 8];
#pragma unroll
    for (int ct = 0; ct < 4; ++ct) {
      bh2[ct] = *(const bf16x8*)&Bhi[wcc * 64 + ct * 16 + lr][lg * 8];
      bl2[ct] = *(const bf16x8*)&Blo[wcc * 64 + ct * 16 + lr][lg * 8];
    }
#pragma unroll
    for (int rt = 0; rt < 4; ++rt)
#pragma unroll
      for (int ct = 0; ct < 4; ++ct) {
        acc2[rt][ct] = __builtin_amdgcn_mfma_f32_16x16x32_bf16(av2[rt], bl2[ct], acc2[rt][ct], 0, 0, 0);
        acc2[rt][ct] = __builtin_amdgcn_mfma_f32_16x16x32_bf16(av2[rt], bh2[ct], acc2[rt][ct], 0, 0, 0);
      }
  }

  // epilogue (no atomics)
  float s1[4][4], s2[4][4];
#pragma unroll
  for (int rt = 0; rt < 4; ++rt)
#pragma unroll
    for (int q = 0; q < 4; ++q) { s1[rt][q] = 0.f; s2[rt][q] = 0.f; }
#pragma unroll
  for (int rt = 0; rt < 4; ++rt)
#pragma unroll
    for (int ct = 0; ct < 4; ++ct) {
      const float bb = b2s[wcc * 64 + ct * 16 + lr];
#pragma unroll
      for (int q = 0; q < 4; ++q) {
        float v = acc2[rt][ct][q] + bb;
        acc2[rt][ct][q] = v;
        s1[rt][q] += v;
        s2[rt][q] += v * v;
      }
    }
#pragma unroll
  for (int m = 1; m < 16; m <<= 1) {
#pragma unroll
    for (int rt = 0; rt < 4; ++rt)
#pragma unroll
      for (int q = 0; q < 4; ++q) {
        s1[rt][q] += __shfl_xor(s1[rt][q], m);
        s2[rt][q] += __shfl_xor(s2[rt][q], m);
      }
  }
  __syncthreads();
  {
    const int rt = lr >> 2, q = lr & 3;
    const int rr = wr * 64 + rt * 16 + lg * 4 + q;
    sumL[wcc][rr] = s1[rt][q];
    sqL[wcc][rr]  = s2[rt][q];
  }
  __syncthreads();
  if (t < 128) {
    const float tot = sumL[0][t] + sumL[1][t];
    const float tsq = sqL[0][t] + sqL[1][t];
    const float mu  = tot * (1.0f / 128.0f);
    const float var = tsq * (1.0f / 128.0f) - mu * mu;
    muL[t] = mu;
    rsL[t] = rsqrtf(var + 1e-5f);
  }
  __syncthreads();

#pragma unroll
  for (int rt = 0; rt < 4; ++rt) {
#pragma unroll
    for (int q = 0; q < 4; ++q) {
      const int rr = wr * 64 + rt * 16 + lg * 4 + q;
      const int grow = row0 + rr;
      if (grow < P.nRows) {
        const float mu = muL[rr], rs = rsL[rr];
        const float* rin = P.attrIn + (size_t)grow * LDIM;
        float* rout = P.attrOut + (size_t)grow * LDIM;
#pragma unroll
        for (int ct = 0; ct < 4; ++ct) {
          const int cc = wcc * 64 + ct * 16 + lr;
          rout[cc] = gs[cc] * (acc2[rt][ct][q] - mu) * rs + bes[cc] + rin[cc];
        }
      }
    }
  }
}

// ============ NODE kernel: CSR gather HOISTED into register accumulators ====
__launch_bounds__(256, 2)
__global__ void node_kernel(MlpParams P) {
  const int bid  = (int)blockIdx.x;
  const int row0 = bid * 128;

  __shared__ __align__(16) short Abuf[128][40];
  __shared__ __align__(16) short Bhi[128][40];
  __shared__ __align__(16) short Blo[128][40];
  __shared__ __align__(16) short Hbuf[128][136];
  __shared__ float b1s[128], b2s[128], gs[128], bes[128];
  __shared__ float sumL[2][128], sqL[2][128];
  __shared__ float muL[128], rsL[128];

  const int t = threadIdx.x;
  if (t < 128) { b1s[t] = P.b1[t]; gs[t] = P.gam[t]; }
  else         { b2s[t - 128] = P.b2[t - 128]; bes[t - 128] = P.bet[t - 128]; }

  const int l   = t & 63;
  const int wid = t >> 6;
  const int wr  = wid >> 1, wcc = wid & 1;
  const int lr  = l & 15,  lg  = l >> 4;

  const int  srow  = t >> 1, sh = t & 1;
  const int  sgRow = row0 + srow;
  const bool sval  = sgRow < P.nRows;
  const int  sgC   = sval ? sgRow : 0;

  const int wrow = t >> 1, wsh = t & 1;
  const short* w1base = P.W1H + (size_t)wrow * 384 + wsh * 16;
  const short* xrow   = P.xb + (size_t)sgC * LDIM + sh * 16;
  const bf16x8 z8 = {0, 0, 0, 0, 0, 0, 0, 0};

  f32x4 acc[4][4];
#pragma unroll
  for (int i = 0; i < 4; ++i)
#pragma unroll
    for (int j = 0; j < 4; ++j) acc[i][j] = f32x4{0.f, 0.f, 0.f, 0.f};

  // ---- hoisted MESH gather: one CSR walk, 64 cols/thread in 16 f32x4 regs ----
  // g[part*4+j] holds cols part*32 + sh*16 + j*4 (exactly the 4 chunks kc=4..7)
  f32x4 g[16];
#pragma unroll
  for (int j = 0; j < 16; ++j) g[j] = f32x4{0.f, 0.f, 0.f, 0.f};
  float scm = 1.f;
  {
    int beg = 0, end = 0;
    if (sval) { beg = P.off1[sgRow]; end = P.off1[sgRow + 1]; }
    for (int i = beg; i < end; ++i) {
      const float* er = P.gsrc1 + (size_t)P.csr1[i] * LDIM + sh * 16;
#pragma unroll
      for (int part = 0; part < 4; ++part) {
        const f32x4* p = (const f32x4*)(er + part * 32);
#pragma unroll
        for (int j = 0; j < 4; ++j) g[part * 4 + j] += p[j];
      }
    }
    scm = 1.0f / (float)max(end - beg, 1);
  }

  __syncthreads();   // small tables ready

  // phase 1: kc0-3 = x (bf16 copy), kc4-7 = mesh mean (regs), kc8-11 = world mean
  float scw = 1.f;
#pragma unroll
  for (int kc = 0; kc < 12; ++kc) {
    const int seg = kc >> 2, part = kc & 3;
    if (kc > 0) __syncthreads();
    {
      if (seg == 0) {
        const bf16x8* xp = (const bf16x8*)(xrow + part * 32);
        *(bf16x8*)&Abuf[srow][sh * 16]     = sval ? xp[0] : z8;
        *(bf16x8*)&Abuf[srow][sh * 16 + 8] = sval ? xp[1] : z8;
      } else {
        const float sc = (seg == 1) ? scm : scw;
        *(bf16x4*)&Abuf[srow][sh * 16 + 0]  = cvt4v(g[part * 4 + 0], sc);
        *(bf16x4*)&Abuf[srow][sh * 16 + 4]  = cvt4v(g[part * 4 + 1], sc);
        *(bf16x4*)&Abuf[srow][sh * 16 + 8]  = cvt4v(g[part * 4 + 2], sc);
        *(bf16x4*)&Abuf[srow][sh * 16 + 12] = cvt4v(g[part * 4 + 3], sc);
      }
      const short* wsrc = w1base + kc * 32;
      *(bf16x8*)&Bhi[wrow][wsh * 16]     = *(const bf16x8*)wsrc;
      *(bf16x8*)&Bhi[wrow][wsh * 16 + 8] = *(const bf16x8*)(wsrc + 8);
      if (kc == 7) {
        // mesh regs fully consumed: reuse g for WORLD gather (feeds kc8-11)
#pragma unroll
        for (int j = 0; j < 16; ++j) g[j] = f32x4{0.f, 0.f, 0.f, 0.f};
        int beg = 0, end = 0;
        if (sval) { beg = P.off2[sgRow]; end = P.off2[sgRow + 1]; }
        for (int i = beg; i < end; ++i) {
          const float* er = P.gsrc2 + (size_t)P.csr2[i] * LDIM + sh * 16;
#pragma unroll
          for (int pp = 0; pp < 4; ++pp) {
            const f32x4* p = (const f32x4*)(er + pp * 32);
#pragma unroll
            for (int j = 0; j < 4; ++j) g[pp * 4 + j] += p[j];
          }
        }
        scw = 1.0f / (float)max(end - beg, 1);
      }
    }
    __syncthreads();
    bf16x8 av[4], bh[4];
#pragma unroll
    for (int mi = 0; mi < 4; ++mi)
      av[mi] = *(const bf16x8*)&Abuf[wr * 64 + mi * 16 + lr][lg * 8];
#pragma unroll
    for (int ni = 0; ni < 4; ++ni)
      bh[ni] = *(const bf16x8*)&Bhi[wcc * 64 + ni * 16 + lr][lg * 8];
#pragma unroll
    for (int mi = 0; mi < 4; ++mi)
#pragma unroll
      for (int ni = 0; ni < 4; ++ni)
        acc[mi][ni] = __builtin_amdgcn_mfma_f32_16x16x32_bf16(av[mi], bh[ni], acc[mi][ni], 0, 0, 0);
  }

  // H write (acc dies)
#pragma unroll
  for (int rt = 0; rt < 4; ++rt)
#pragma unroll
    for (int ct = 0; ct < 4; ++ct) {
      const int cc = wcc * 64 + ct * 16 + lr;
      const float bb = b1s[cc];
#pragma unroll
      for (int q = 0; q < 4; ++q) {
        const int rr = wr * 64 + rt * 16 + lg * 4 + q;
        Hbuf[rr][cc] = f2b(fmaxf(acc[rt][ct][q] + bb, 0.f));
      }
    }

  // phase 2 (W2 hi/lo)
  f32x4 acc2[4][4];
#pragma unroll
  for (int i = 0; i < 4; ++i)
#pragma unroll
    for (int j = 0; j < 4; ++j) acc2[i][j] = f32x4{0.f, 0.f, 0.f, 0.f};

  const short* w2hbase = P.W2H + (size_t)wrow * 128 + wsh * 16;
  const short* w2lbase = P.W2L + (size_t)wrow * 128 + wsh * 16;
  bf16x8 qh0 = *(const bf16x8*)w2hbase;
  bf16x8 qh1 = *(const bf16x8*)(w2hbase + 8);
  bf16x8 ql0 = *(const bf16x8*)w2lbase;
  bf16x8 ql1 = *(const bf16x8*)(w2lbase + 8);

#pragma unroll
  for (int kc = 0; kc < 4; ++kc) {
    __syncthreads();
    {
      *(bf16x8*)&Bhi[wrow][wsh * 16]     = qh0;
      *(bf16x8*)&Bhi[wrow][wsh * 16 + 8] = qh1;
      *(bf16x8*)&Blo[wrow][wsh * 16]     = ql0;
      *(bf16x8*)&Blo[wrow][wsh * 16 + 8] = ql1;
    }
    __syncthreads();
    if (kc < 3) {
      qh0 = *(const bf16x8*)(w2hbase + (kc + 1) * 32);
      qh1 = *(const bf16x8*)(w2hbase + (kc + 1) * 32 + 8);
      ql0 = *(const bf16x8*)(w2lbase + (kc + 1) * 32);
      ql1 = *(const bf16x8*)(w2lbase + (kc + 1) * 32 + 8);
    }
    bf16x8 av2[4], bh2[4], bl2[4];
#pragma unroll
    for (int rt = 0; rt < 4; ++rt)
      av2[rt] = *(const bf16x8*)&Hbuf[wr * 64 + rt * 16 + lr][kc * 32 + lg * 8];
#pragma unroll
    for (int ct = 0; ct < 4; ++ct) {
      bh2[ct] = *(const bf16x8*)&Bhi[wcc * 64 + ct * 16 + lr][lg * 8];
      bl2[ct] = *(const bf16x8*)&Blo[wcc * 64 + ct * 16 + lr][lg * 8];
    }
#pragma unroll
    for (int rt = 0; rt < 4; ++rt)
#pragma unroll
      for (int ct = 0; ct < 4; ++ct) {
        acc2[rt][ct] = __builtin_amdgcn_mfma_f32_16x16x32_bf16(av2[rt], bl2[ct], acc2[rt][ct], 0, 0, 0);
        acc2[rt][ct] = __builtin_amdgcn_mfma_f32_16x16x32_bf16(av2[rt], bh2[ct], acc2[rt][ct], 0, 0, 0);
      }
  }

  // epilogue
  float s1[4][4], s2[4][4];
#pragma unroll
  for (int rt = 0; rt < 4; ++rt)
#pragma unroll
    for (int q = 0; q < 4; ++q) { s1[rt][q] = 0.f; s2[rt][q] = 0.f; }
#pragma unroll
  for (int rt = 0; rt < 4; ++rt)
#pragma unroll
    for (int ct = 0; ct < 4; ++ct) {
      const float bb = b2s[wcc * 64 + ct * 16 + lr];
#pragma unroll
      for (int q = 0; q < 4; ++q) {
        float v = acc2[rt][ct][q] + bb;
        acc2[rt][ct][q] = v;
        s1[rt][q] += v;
        s2[rt][q] += v * v;
      }
    }
#pragma unroll
  for (int m = 1; m < 16; m <<= 1) {
#pragma unroll
    for (int rt = 0; rt < 4; ++rt)
#pragma unroll
      for (int q = 0; q < 4; ++q) {
        s1[rt][q] += __shfl_xor(s1[rt][q], m);
        s2[rt][q] += __shfl_xor(s2[rt][q], m);
      }
  }
  __syncthreads();
  {
    const int rt = lr >> 2, q = lr & 3;
    const int rr = wr * 64 + rt * 16 + lg * 4 + q;
    sumL[wcc][rr] = s1[rt][q];
    sqL[wcc][rr]  = s2[rt][q];
  }
  __syncthreads();
  if (t < 128) {
    const float tot = sumL[0][t] + sumL[1][t];
    const float tsq = sqL[0][t] + sqL[1][t];
    const float mu  = tot * (1.0f / 128.0f);
    const float var = tsq * (1.0f / 128.0f) - mu * mu;
    muL[t] = mu;
    rsL[t] = rsqrtf(var + 1e-5f);
  }
  __syncthreads();

#pragma unroll
  for (int rt = 0; rt < 4; ++rt) {
#pragma unroll
    for (int q = 0; q < 4; ++q) {
      const int rr = wr * 64 + rt * 16 + lg * 4 + q;
      const int grow = row0 + rr;
      if (grow < P.nRows) {
        const float mu = muL[rr], rs = rsL[rr];
        const float* rin = P.attrIn + (size_t)grow * LDIM;
        float* rout = P.attrOut + (size_t)grow * LDIM;
        short* xbo  = P.xbOut + (size_t)grow * LDIM;
#pragma unroll
        for (int ct = 0; ct < 4; ++ct) {
          const int cc = wcc * 64 + ct * 16 + lr;
          const float o = gs[cc] * (acc2[rt][ct][q] - mu) * rs + bes[cc] + rin[cc];
          rout[cc] = o;
          xbo[cc] = f2b(o);   // bf16 copy for next step's edge gathers
        }
      }
    }
  }
}

// ---- prep kernels ----
__global__ void prep_weights(const float* w1a, const float* w1b, const float* w1c,
                             const float* w2a, const float* w2b, const float* w2c,
                             short* w1h, short* w2h, short* w2l) {
  int i = blockIdx.x * 256 + threadIdx.x;
  constexpr int N1 = 18 * 128 * 384;
  constexpr int N2 = 18 * 128 * 128;
  if (i < N1) {
    int g = i / (128 * 384);
    int rem = i - g * (128 * 384);
    int n = rem / 384, k = rem - n * 384;
    int m = g / 6, s = g - m * 6;
    const float* src = (m == 0) ? w1a : (m == 1) ? w1b : w1c;
    w1h[i] = f2b(src[(size_t)s * (384 * 128) + (size_t)k * 128 + n]);
  } else if (i < N1 + N2) {
    int j = i - N1;
    int g = j / (128 * 128);
    int rem = j - g * (128 * 128);
    int n = rem / 128, k = rem - n * 128;
    int m = g / 6, s = g - m * 6;
    const float* src = (m == 0) ? w2a : (m == 1) ? w2b : w2c;
    float f = src[(size_t)s * (128 * 128) + (size_t)k * 128 + n];
    short hi = f2b(f);
    w2h[j] = hi;
    w2l[j] = f2b(f - b2f(hi));
  }
}

__global__ void prep_xb(const float* x, short* xb) {
  int i = blockIdx.x * 256 + threadIdx.x;
  if (i < NNODE * LDIM) xb[i] = f2b(x[i]);
}

__global__ void prep_deg(const int* mr, const int* wrcv, int* degm, int* degw) {
  int i = blockIdx.x * 256 + threadIdx.x;
  if (i < EM_N) atomicAdd(&degm[mr[i]], 1);
  else if (i < EM_N + EW_N) atomicAdd(&degw[wrcv[i - EM_N]], 1);
}

// single-block exclusive scan: degm->moff, degw->woff
__global__ void prep_scan(const int* degm, const int* degw, int* moff, int* woff) {
  __shared__ int part[256];
  const int t = threadIdx.x;
  constexpr int NPT = (NNODE + 255) / 256;
#pragma unroll 1
  for (int pass = 0; pass < 2; ++pass) {
    const int* deg = pass == 0 ? degm : degw;
    int* off = pass == 0 ? moff : woff;
    int s = 0;
    for (int i = 0; i < NPT; ++i) {
      int n = t * NPT + i;
      if (n < NNODE) s += deg[n];
    }
    part[t] = s;
    __syncthreads();
    for (int d = 1; d < 256; d <<= 1) {
      int v = (t >= d) ? part[t - d] : 0;
      __syncthreads();
      part[t] += v;
      __syncthreads();
    }
    int base = (t == 0) ? 0 : part[t - 1];
    for (int i = 0; i < NPT; ++i) {
      int n = t * NPT + i;
      if (n < NNODE) { off[n] = base; base += deg[n]; }
    }
    if (t == 255) off[NNODE] = base;
    __syncthreads();
  }
}

__global__ void prep_fill(const int* mr, const int* wrcv,
                          const int* moff, const int* woff,
                          int* mcur, int* wcur, int* mcsr, int* wcsr) {
  int i = blockIdx.x * 256 + threadIdx.x;
  if (i < EM_N) {
    int d = mr[i];
    int pos = moff[d] + atomicAdd(&mcur[d], 1);
    mcsr[pos] = i;
  } else if (i < EM_N + EW_N) {
    int j = i - EM_N;
    int d = wrcv[j];
    int pos = woff[d] + atomicAdd(&wcur[d], 1);
    wcsr[pos] = j;
  }
}

extern "C" void kernel_launch(void* const* d_in, const int* in_sizes, int n_in,
                              void* d_out, int out_size, void* d_ws, size_t ws_size,
                              hipStream_t stream) {
  (void)in_sizes; (void)n_in; (void)out_size; (void)ws_size;
  const float* x_in   = (const float*)d_in[0];
  const float* mea_in = (const float*)d_in[1];
  const float* wea_in = (const float*)d_in[2];
  const int*   mei    = (const int*)d_in[3];
  const int*   wei    = (const int*)d_in[4];
  const float* W1s[3] = { (const float*)d_in[5],  (const float*)d_in[11], (const float*)d_in[17] };
  const float* B1s[3] = { (const float*)d_in[6],  (const float*)d_in[12], (const float*)d_in[18] };
  const float* W2s[3] = { (const float*)d_in[7],  (const float*)d_in[13], (const float*)d_in[19] };
  const float* B2s[3] = { (const float*)d_in[8],  (const float*)d_in[14], (const float*)d_in[20] };
  const float* Gs[3]  = { (const float*)d_in[9],  (const float*)d_in[15], (const float*)d_in[21] };
  const float* Be[3]  = { (const float*)d_in[10], (const float*)d_in[16], (const float*)d_in[22] };

  float* xo  = (float*)d_out;
  float* meo = xo  + (size_t)NNODE * LDIM;
  float* weo = meo + (size_t)EM_N * LDIM;

  int*   degm = (int*)d_ws;
  int*   degw = degm + NNODE;
  int*   mcur = degw + NNODE;
  int*   wcur = mcur + NNODE;
  int*   moff = wcur + NNODE;
  int*   woff = moff + (NNODE + 1);
  int*   mcsr = woff + (NNODE + 1);
  int*   wcsr = mcsr + EM_N;
  short* w1h  = (short*)(wcsr + EW_N);
  short* w2h  = w1h + (size_t)18 * 128 * 384;
  short* w2l  = w2h + (size_t)18 * 128 * 128;
  short* xb   = w2l + (size_t)18 * 128 * 128;

  hipMemsetAsync(d_ws, 0, (size_t)4 * NNODE * 4, stream);  // degm,degw,mcur,wcur

  {
    int tot = 18 * 128 * 384 + 18 * 128 * 128;
    prep_weights<<<dim3((tot + 255) / 256), 256, 0, stream>>>(
        W1s[0], W1s[1], W1s[2], W2s[0], W2s[1], W2s[2], w1h, w2h, w2l);
  }
  prep_xb<<<dim3((NNODE * LDIM + 255) / 256), 256, 0, stream>>>(x_in, xb);
  prep_deg<<<dim3((EM_N + EW_N + 255) / 256), 256, 0, stream>>>(mei + EM_N, wei + EW_N, degm, degw);
  prep_scan<<<dim3(1), 256, 0, stream>>>(degm, degw, moff, woff);
  prep_fill<<<dim3((EM_N + EW_N + 255) / 256), 256, 0, stream>>>(
      mei + EM_N, wei + EW_N, moff, woff, mcur, wcur, mcsr, wcsr);

  const int MB = (EM_N + 127) / 128;   // 782
  const int WB = (EW_N + 127) / 128;   // 196
  const int NB = (NNODE + 127) / 128;  // 157

  const float* mc = mea_in;
  const float* wc = wea_in;
  const float* xc = x_in;

  for (int s = 0; s < NSTEP; ++s) {
    MlpParams pm{}, pw{}, pn{};

    pm.xb = xb; pm.attrIn = mc; pm.attrOut = meo;
    pm.src = mei; pm.dst = mei + EM_N;
    pm.W1H = w1h + (size_t)(0 * 6 + s) * 128 * 384;
    pm.W2H = w2h + (size_t)(0 * 6 + s) * 128 * 128;
    pm.W2L = w2l + (size_t)(0 * 6 + s) * 128 * 128;
    pm.b1 = B1s[0] + s * LDIM; pm.b2 = B2s[0] + s * LDIM;
    pm.gam = Gs[0] + s * LDIM; pm.bet = Be[0] + s * LDIM;
    pm.nRows = EM_N;

    pw.xb = xb; pw.attrIn = wc; pw.attrOut = weo;
    pw.src = wei; pw.dst = wei + EW_N;
    pw.W1H = w1h + (size_t)(1 * 6 + s) * 128 * 384;
    pw.W2H = w2h + (size_t)(1 * 6 + s) * 128 * 128;
    pw.W2L = w2l + (size_t)(1 * 6 + s) * 128 * 128;
    pw.b1 = B1s[1] + s * LDIM; pw.b2 = B2s[1] + s * LDIM;
    pw.gam = Gs[1] + s * LDIM; pw.bet = Be[1] + s * LDIM;
    pw.nRows = EW_N;

    edge_kernel<<<dim3(MB + WB), 256, 0, stream>>>(pm, pw, MB);

    pn.xb = xb; pn.attrIn = xc; pn.attrOut = xo; pn.xbOut = xb;
    pn.gsrc1 = meo; pn.gsrc2 = weo;
    pn.off1 = moff; pn.csr1 = mcsr;
    pn.off2 = woff; pn.csr2 = wcsr;
    pn.W1H = w1h + (size_t)(2 * 6 + s) * 128 * 384;
    pn.W2H = w2h + (size_t)(2 * 6 + s) * 128 * 128;
    pn.W2L = w2l + (size_t)(2 * 6 + s) * 128 * 128;
    pn.b1 = B1s[2] + s * LDIM; pn.b2 = B2s[2] + s * LDIM;
    pn.gam = Gs[2] + s * LDIM; pn.bet = Be[2] + s * LDIM;
    pn.nRows = NNODE;

    node_kernel<<<dim3(NB), 256, 0, stream>>>(pn);

    mc = meo; wc = weo; xc = xo;
  }
}

// Round 14
// 852.474 us; speedup vs baseline: 1.2122x; 1.0452x over previous
//
#include <hip/hip_runtime.h>

constexpr int LDIM  = 128;
constexpr int NNODE = 20000;
constexpr int EM_N  = 100000;
constexpr int EW_N  = 25000;
constexpr int NSTEP = 6;

typedef short bf16x8 __attribute__((ext_vector_type(8)));
typedef short bf16x4 __attribute__((ext_vector_type(4)));
typedef float f32x4  __attribute__((ext_vector_type(4)));

struct MlpParams {
  const short* xb;      // bf16 node features (gather source)
  const float* attrIn;  // residual input (f32)
  float*       attrOut;
  short*       xbOut;   // node: bf16 copy of new x
  const int*   src;
  const int*   dst;
  const int*   oidx;    // edge, last step: sorted pos -> original edge id
  float*       origOut; // edge, last step: d_out region (original order)
  const float* gsrc1;   // node: mesh edge attr (gather source)
  const float* gsrc2;   // node: world edge attr
  const int*   off1;    // node: mesh CSR offsets [NNODE+1]
  const int*   csr1;    // node: mesh CSR edge ids (CSR mode only)
  const int*   off2;
  const int*   csr2;
  const short* W1H;     // bf16 [128 n][384 k]
  const short* W2H;     // bf16 hi [128 n][128 k]
  const short* W2L;     // bf16 lo
  const float* b1;
  const float* b2;
  const float* gam;
  const float* bet;
  int nRows;
};

__device__ __forceinline__ short f2b(float f) {
  unsigned int u = __float_as_uint(f);
  u = (u + 0x7fffu + ((u >> 16) & 1u)) >> 16;
  return (short)u;
}
__device__ __forceinline__ float b2f(short s) {
  return __uint_as_float(((unsigned int)(unsigned short)s) << 16);
}
__device__ __forceinline__ bf16x4 cvt4(float4 a, float sc) {
  bf16x4 o;
  o[0] = f2b(a.x * sc); o[1] = f2b(a.y * sc);
  o[2] = f2b(a.z * sc); o[3] = f2b(a.w * sc);
  return o;
}
__device__ __forceinline__ bf16x4 cvt4v(f32x4 a, float sc) {
  bf16x4 o;
  o[0] = f2b(a[0] * sc); o[1] = f2b(a[1] * sc);
  o[2] = f2b(a[2] * sc); o[3] = f2b(a[3] * sc);
  return o;
}

// ================= EDGE kernel (R13 structure; optional dual-write) =========
__launch_bounds__(256, 2)
__global__ void edge_kernel(MlpParams pmA, MlpParams pmB, int blocksA) {
  const bool isA = (int)blockIdx.x < blocksA;
  const MlpParams P = isA ? pmA : pmB;
  const int bid  = isA ? (int)blockIdx.x : (int)blockIdx.x - blocksA;
  const int row0 = bid * 128;

  __shared__ __align__(16) short Abuf[128][40];
  __shared__ __align__(16) short Bhi[128][40];
  __shared__ __align__(16) short Blo[128][40];
  __shared__ __align__(16) short Hbuf[128][136];
  __shared__ float b1s[128], b2s[128], gs[128], bes[128];
  __shared__ int   idxa[128], idxb[128];
  __shared__ float sumL[2][128], sqL[2][128];
  __shared__ float muL[128], rsL[128];

  const int t = threadIdx.x;

  if (t < 128) {
    b1s[t] = P.b1[t];
    gs[t]  = P.gam[t];
    int r = row0 + t;
    idxa[t] = (r < P.nRows) ? P.src[r] : 0;
  } else {
    int t2 = t - 128;
    b2s[t2] = P.b2[t2];
    bes[t2] = P.bet[t2];
    int r = row0 + t2;
    idxb[t2] = (r < P.nRows) ? P.dst[r] : 0;
  }
  __syncthreads();

  const int l   = t & 63;
  const int wid = t >> 6;
  const int wr  = wid >> 1, wcc = wid & 1;
  const int lr  = l & 15,  lg  = l >> 4;

  const int  srow  = t >> 1, sh = t & 1;
  const int  sgRow = row0 + srow;
  const bool sval  = sgRow < P.nRows;
  const int  sgC   = sval ? sgRow : 0;
  const float vmask = sval ? 1.f : 0.f;

  const short* bx0   = P.xb + (size_t)idxa[srow] * LDIM + sh * 16;
  const short* bx1   = P.xb + (size_t)idxb[srow] * LDIM + sh * 16;
  const float* base2 = P.attrIn + (size_t)sgC * LDIM + sh * 16;

  const int wrow = t >> 1, wsh = t & 1;
  const short* w1base = P.W1H + (size_t)wrow * 384 + wsh * 16;

  f32x4 acc[4][4];
#pragma unroll
  for (int i = 0; i < 4; ++i)
#pragma unroll
    for (int j = 0; j < 4; ++j) acc[i][j] = f32x4{0.f, 0.f, 0.f, 0.f};

  const bf16x8 z8 = {0, 0, 0, 0, 0, 0, 0, 0};
  bf16x8 pB0, pB1;
  float4 pA0, pA1, pA2, pA3;
  bf16x8 pW0, pW1;
  {
    pB0 = *(const bf16x8*)bx0;
    pB1 = *(const bf16x8*)(bx0 + 8);
    pW0 = *(const bf16x8*)w1base;
    pW1 = *(const bf16x8*)(w1base + 8);
  }

  // phase 1
#pragma unroll
  for (int kc = 0; kc < 12; ++kc) {
    const int seg = kc >> 2;
    if (kc > 0) __syncthreads();
    {
      if (seg < 2) {
        *(bf16x8*)&Abuf[srow][sh * 16]     = sval ? pB0 : z8;
        *(bf16x8*)&Abuf[srow][sh * 16 + 8] = sval ? pB1 : z8;
      } else {
        *(bf16x4*)&Abuf[srow][sh * 16 + 0]  = cvt4(pA0, vmask);
        *(bf16x4*)&Abuf[srow][sh * 16 + 4]  = cvt4(pA1, vmask);
        *(bf16x4*)&Abuf[srow][sh * 16 + 8]  = cvt4(pA2, vmask);
        *(bf16x4*)&Abuf[srow][sh * 16 + 12] = cvt4(pA3, vmask);
      }
      *(bf16x8*)&Bhi[wrow][wsh * 16]     = pW0;
      *(bf16x8*)&Bhi[wrow][wsh * 16 + 8] = pW1;
    }
    __syncthreads();
    if (kc < 11) {
      const int kn = kc + 1, segn = kn >> 2, partn = kn & 3;
      if (segn == 0) {
        pB0 = *(const bf16x8*)(bx0 + partn * 32);
        pB1 = *(const bf16x8*)(bx0 + partn * 32 + 8);
      } else if (segn == 1) {
        pB0 = *(const bf16x8*)(bx1 + partn * 32);
        pB1 = *(const bf16x8*)(bx1 + partn * 32 + 8);
      } else {
        const float4* bp = (const float4*)(base2 + partn * 32);
        pA0 = bp[0]; pA1 = bp[1]; pA2 = bp[2]; pA3 = bp[3];
      }
      pW0 = *(const bf16x8*)(w1base + kn * 32);
      pW1 = *(const bf16x8*)(w1base + kn * 32 + 8);
    }
    bf16x8 av[4], bh[4];
#pragma unroll
    for (int mi = 0; mi < 4; ++mi)
      av[mi] = *(const bf16x8*)&Abuf[wr * 64 + mi * 16 + lr][lg * 8];
#pragma unroll
    for (int ni = 0; ni < 4; ++ni)
      bh[ni] = *(const bf16x8*)&Bhi[wcc * 64 + ni * 16 + lr][lg * 8];
#pragma unroll
    for (int mi = 0; mi < 4; ++mi)
#pragma unroll
      for (int ni = 0; ni < 4; ++ni)
        acc[mi][ni] = __builtin_amdgcn_mfma_f32_16x16x32_bf16(av[mi], bh[ni], acc[mi][ni], 0, 0, 0);
  }

  // H write (acc dies)
#pragma unroll
  for (int rt = 0; rt < 4; ++rt)
#pragma unroll
    for (int ct = 0; ct < 4; ++ct) {
      const int cc = wcc * 64 + ct * 16 + lr;
      const float bb = b1s[cc];
#pragma unroll
      for (int q = 0; q < 4; ++q) {
        const int rr = wr * 64 + rt * 16 + lg * 4 + q;
        Hbuf[rr][cc] = f2b(fmaxf(acc[rt][ct][q] + bb, 0.f));
      }
    }

  // phase 2 (W2 hi/lo, prefetched)
  f32x4 acc2[4][4];
#pragma unroll
  for (int i = 0; i < 4; ++i)
#pragma unroll
    for (int j = 0; j < 4; ++j) acc2[i][j] = f32x4{0.f, 0.f, 0.f, 0.f};

  const short* w2hbase = P.W2H + (size_t)wrow * 128 + wsh * 16;
  const short* w2lbase = P.W2L + (size_t)wrow * 128 + wsh * 16;

  bf16x8 qh0 = *(const bf16x8*)w2hbase;
  bf16x8 qh1 = *(const bf16x8*)(w2hbase + 8);
  bf16x8 ql0 = *(const bf16x8*)w2lbase;
  bf16x8 ql1 = *(const bf16x8*)(w2lbase + 8);

#pragma unroll
  for (int kc = 0; kc < 4; ++kc) {
    __syncthreads();
    {
      *(bf16x8*)&Bhi[wrow][wsh * 16]     = qh0;
      *(bf16x8*)&Bhi[wrow][wsh * 16 + 8] = qh1;
      *(bf16x8*)&Blo[wrow][wsh * 16]     = ql0;
      *(bf16x8*)&Blo[wrow][wsh * 16 + 8] = ql1;
    }
    __syncthreads();
    if (kc < 3) {
      qh0 = *(const bf16x8*)(w2hbase + (kc + 1) * 32);
      qh1 = *(const bf16x8*)(w2hbase + (kc + 1) * 32 + 8);
      ql0 = *(const bf16x8*)(w2lbase + (kc + 1) * 32);
      ql1 = *(const bf16x8*)(w2lbase + (kc + 1) * 32 + 8);
    }
    bf16x8 av2[4], bh2[4], bl2[4];
#pragma unroll
    for (int rt = 0; rt < 4; ++rt)
      av2[rt] = *(const bf16x8*)&Hbuf[wr * 64 + rt * 16 + lr][kc * 32 + lg * 8];
#pragma unroll
    for (int ct = 0; ct < 4; ++ct) {
      bh2[ct] = *(const bf16x8*)&Bhi[wcc * 64 + ct * 16 + lr][lg * 8];
      bl2[ct] = *(const bf16x8*)&Blo[wcc * 64 + ct * 16 + lr][lg * 8];
    }
#pragma unroll
    for (int rt = 0; rt < 4; ++rt)
#pragma unroll
      for (int ct = 0; ct < 4; ++ct) {
        acc2[rt][ct] = __builtin_amdgcn_mfma_f32_16x16x32_bf16(av2[rt], bl2[ct], acc2[rt][ct], 0, 0, 0);
        acc2[rt][ct] = __builtin_amdgcn_mfma_f32_16x16x32_bf16(av2[rt], bh2[ct], acc2[rt][ct], 0, 0, 0);
      }
  }

  // epilogue
  float s1[4][4], s2[4][4];
#pragma unroll
  for (int rt = 0; rt < 4; ++rt)
#pragma unroll
    for (int q = 0; q < 4; ++q) { s1[rt][q] = 0.f; s2[rt][q] = 0.f; }
#pragma unroll
  for (int rt = 0; rt < 4; ++rt)
#pragma unroll
    for (int ct = 0; ct < 4; ++ct) {
      const float bb = b2s[wcc * 64 + ct * 16 + lr];
#pragma unroll
      for (int q = 0; q < 4; ++q) {
        float v = acc2[rt][ct][q] + bb;
        acc2[rt][ct][q] = v;
        s1[rt][q] += v;
        s2[rt][q] += v * v;
      }
    }
#pragma unroll
  for (int m = 1; m < 16; m <<= 1) {
#pragma unroll
    for (int rt = 0; rt < 4; ++rt)
#pragma unroll
      for (int q = 0; q < 4; ++q) {
        s1[rt][q] += __shfl_xor(s1[rt][q], m);
        s2[rt][q] += __shfl_xor(s2[rt][q], m);
      }
  }
  __syncthreads();
  {
    const int rt = lr >> 2, q = lr & 3;
    const int rr = wr * 64 + rt * 16 + lg * 4 + q;
    sumL[wcc][rr] = s1[rt][q];
    sqL[wcc][rr]  = s2[rt][q];
  }
  __syncthreads();
  if (t < 128) {
    const float tot = sumL[0][t] + sumL[1][t];
    const float tsq = sqL[0][t] + sqL[1][t];
    const float mu  = tot * (1.0f / 128.0f);
    const float var = tsq * (1.0f / 128.0f) - mu * mu;
    muL[t] = mu;
    rsL[t] = rsqrtf(var + 1e-5f);
  }
  __syncthreads();

#pragma unroll
  for (int rt = 0; rt < 4; ++rt) {
#pragma unroll
    for (int q = 0; q < 4; ++q) {
      const int rr = wr * 64 + rt * 16 + lg * 4 + q;
      const int grow = row0 + rr;
      if (grow < P.nRows) {
        const float mu = muL[rr], rs = rsL[rr];
        const float* rin = P.attrIn + (size_t)grow * LDIM;
        float* rout = P.attrOut + (size_t)grow * LDIM;
        float* rout2 = nullptr;
        if (P.origOut) rout2 = P.origOut + (size_t)P.oidx[grow] * LDIM;
#pragma unroll
        for (int ct = 0; ct < 4; ++ct) {
          const int cc = wcc * 64 + ct * 16 + lr;
          const float o = gs[cc] * (acc2[rt][ct][q] - mu) * rs + bes[cc] + rin[cc];
          rout[cc] = o;
          if (rout2) rout2[cc] = o;
        }
      }
    }
  }
}

// ============ NODE kernel: gather (CONTIG = dst-sorted layout) ==============
template<bool CONTIG>
__launch_bounds__(256, 2)
__global__ void node_kernel(MlpParams P) {
  const int bid  = (int)blockIdx.x;
  const int row0 = bid * 128;

  __shared__ __align__(16) short Abuf[128][40];
  __shared__ __align__(16) short Bhi[128][40];
  __shared__ __align__(16) short Blo[128][40];
  __shared__ __align__(16) short Hbuf[128][136];
  __shared__ float b1s[128], b2s[128], gs[128], bes[128];
  __shared__ float sumL[2][128], sqL[2][128];
  __shared__ float muL[128], rsL[128];

  const int t = threadIdx.x;
  if (t < 128) { b1s[t] = P.b1[t]; gs[t] = P.gam[t]; }
  else         { b2s[t - 128] = P.b2[t - 128]; bes[t - 128] = P.bet[t - 128]; }

  const int l   = t & 63;
  const int wid = t >> 6;
  const int wr  = wid >> 1, wcc = wid & 1;
  const int lr  = l & 15,  lg  = l >> 4;

  const int  srow  = t >> 1, sh = t & 1;
  const int  sgRow = row0 + srow;
  const bool sval  = sgRow < P.nRows;
  const int  sgC   = sval ? sgRow : 0;

  const int wrow = t >> 1, wsh = t & 1;
  const short* w1base = P.W1H + (size_t)wrow * 384 + wsh * 16;
  const short* xrow   = P.xb + (size_t)sgC * LDIM + sh * 16;
  const bf16x8 z8 = {0, 0, 0, 0, 0, 0, 0, 0};

  f32x4 acc[4][4];
#pragma unroll
  for (int i = 0; i < 4; ++i)
#pragma unroll
    for (int j = 0; j < 4; ++j) acc[i][j] = f32x4{0.f, 0.f, 0.f, 0.f};

  // hoisted MESH gather
  f32x4 g[16];
#pragma unroll
  for (int j = 0; j < 16; ++j) g[j] = f32x4{0.f, 0.f, 0.f, 0.f};
  float scm = 1.f;
  {
    int beg = 0, end = 0;
    if (sval) { beg = P.off1[sgRow]; end = P.off1[sgRow + 1]; }
    for (int i = beg; i < end; ++i) {
      const size_t r = CONTIG ? (size_t)i : (size_t)P.csr1[i];
      const float* er = P.gsrc1 + r * LDIM + sh * 16;
#pragma unroll
      for (int part = 0; part < 4; ++part) {
        const f32x4* p = (const f32x4*)(er + part * 32);
#pragma unroll
        for (int j = 0; j < 4; ++j) g[part * 4 + j] += p[j];
      }
    }
    scm = 1.0f / (float)max(end - beg, 1);
  }

  __syncthreads();

  float scw = 1.f;
#pragma unroll
  for (int kc = 0; kc < 12; ++kc) {
    const int seg = kc >> 2, part = kc & 3;
    if (kc > 0) __syncthreads();
    {
      if (seg == 0) {
        const bf16x8* xp = (const bf16x8*)(xrow + part * 32);
        *(bf16x8*)&Abuf[srow][sh * 16]     = sval ? xp[0] : z8;
        *(bf16x8*)&Abuf[srow][sh * 16 + 8] = sval ? xp[1] : z8;
      } else {
        const float sc = (seg == 1) ? scm : scw;
        *(bf16x4*)&Abuf[srow][sh * 16 + 0]  = cvt4v(g[part * 4 + 0], sc);
        *(bf16x4*)&Abuf[srow][sh * 16 + 4]  = cvt4v(g[part * 4 + 1], sc);
        *(bf16x4*)&Abuf[srow][sh * 16 + 8]  = cvt4v(g[part * 4 + 2], sc);
        *(bf16x4*)&Abuf[srow][sh * 16 + 12] = cvt4v(g[part * 4 + 3], sc);
      }
      const short* wsrc = w1base + kc * 32;
      *(bf16x8*)&Bhi[wrow][wsh * 16]     = *(const bf16x8*)wsrc;
      *(bf16x8*)&Bhi[wrow][wsh * 16 + 8] = *(const bf16x8*)(wsrc + 8);
      if (kc == 7) {
        // mesh regs consumed: reuse g for WORLD gather (feeds kc8-11)
#pragma unroll
        for (int j = 0; j < 16; ++j) g[j] = f32x4{0.f, 0.f, 0.f, 0.f};
        int beg = 0, end = 0;
        if (sval) { beg = P.off2[sgRow]; end = P.off2[sgRow + 1]; }
        for (int i = beg; i < end; ++i) {
          const size_t r = CONTIG ? (size_t)i : (size_t)P.csr2[i];
          const float* er = P.gsrc2 + r * LDIM + sh * 16;
#pragma unroll
          for (int pp = 0; pp < 4; ++pp) {
            const f32x4* p = (const f32x4*)(er + pp * 32);
#pragma unroll
            for (int j = 0; j < 4; ++j) g[pp * 4 + j] += p[j];
          }
        }
        scw = 1.0f / (float)max(end - beg, 1);
      }
    }
    __syncthreads();
    bf16x8 av[4], bh[4];
#pragma unroll
    for (int mi = 0; mi < 4; ++mi)
      av[mi] = *(const bf16x8*)&Abuf[wr * 64 + mi * 16 + lr][lg * 8];
#pragma unroll
    for (int ni = 0; ni < 4; ++ni)
      bh[ni] = *(const bf16x8*)&Bhi[wcc * 64 + ni * 16 + lr][lg * 8];
#pragma unroll
    for (int mi = 0; mi < 4; ++mi)
#pragma unroll
      for (int ni = 0; ni < 4; ++ni)
        acc[mi][ni] = __builtin_amdgcn_mfma_f32_16x16x32_bf16(av[mi], bh[ni], acc[mi][ni], 0, 0, 0);
  }

  // H write (acc dies)
#pragma unroll
  for (int rt = 0; rt < 4; ++rt)
#pragma unroll
    for (int ct = 0; ct < 4; ++ct) {
      const int cc = wcc * 64 + ct * 16 + lr;
      const float bb = b1s[cc];
#pragma unroll
      for (int q = 0; q < 4; ++q) {
        const int rr = wr * 64 + rt * 16 + lg * 4 + q;
        Hbuf[rr][cc] = f2b(fmaxf(acc[rt][ct][q] + bb, 0.f));
      }
    }

  // phase 2 (W2 hi/lo)
  f32x4 acc2[4][4];
#pragma unroll
  for (int i = 0; i < 4; ++i)
#pragma unroll
    for (int j = 0; j < 4; ++j) acc2[i][j] = f32x4{0.f, 0.f, 0.f, 0.f};

  const short* w2hbase = P.W2H + (size_t)wrow * 128 + wsh * 16;
  const short* w2lbase = P.W2L + (size_t)wrow * 128 + wsh * 16;
  bf16x8 qh0 = *(const bf16x8*)w2hbase;
  bf16x8 qh1 = *(const bf16x8*)(w2hbase + 8);
  bf16x8 ql0 = *(const bf16x8*)w2lbase;
  bf16x8 ql1 = *(const bf16x8*)(w2lbase + 8);

#pragma unroll
  for (int kc = 0; kc < 4; ++kc) {
    __syncthreads();
    {
      *(bf16x8*)&Bhi[wrow][wsh * 16]     = qh0;
      *(bf16x8*)&Bhi[wrow][wsh * 16 + 8] = qh1;
      *(bf16x8*)&Blo[wrow][wsh * 16]     = ql0;
      *(bf16x8*)&Blo[wrow][wsh * 16 + 8] = ql1;
    }
    __syncthreads();
    if (kc < 3) {
      qh0 = *(const bf16x8*)(w2hbase + (kc + 1) * 32);
      qh1 = *(const bf16x8*)(w2hbase + (kc + 1) * 32 + 8);
      ql0 = *(const bf16x8*)(w2lbase + (kc + 1) * 32);
      ql1 = *(const bf16x8*)(w2lbase + (kc + 1) * 32 + 8);
    }
    bf16x8 av2[4], bh2[4], bl2[4];
#pragma unroll
    for (int rt = 0; rt < 4; ++rt)
      av2[rt] = *(const bf16x8*)&Hbuf[wr * 64 + rt * 16 + lr][kc * 32 + lg * 8];
#pragma unroll
    for (int ct = 0; ct < 4; ++ct) {
      bh2[ct] = *(const bf16x8*)&Bhi[wcc * 64 + ct * 16 + lr][lg * 8];
      bl2[ct] = *(const bf16x8*)&Blo[wcc * 64 + ct * 16 + lr][lg * 8];
    }
#pragma unroll
    for (int rt = 0; rt < 4; ++rt)
#pragma unroll
      for (int ct = 0; ct < 4; ++ct) {
        acc2[rt][ct] = __builtin_amdgcn_mfma_f32_16x16x32_bf16(av2[rt], bl2[ct], acc2[rt][ct], 0, 0, 0);
        acc2[rt][ct] = __builtin_amdgcn_mfma_f32_16x16x32_bf16(av2[rt], bh2[ct], acc2[rt][ct], 0, 0, 0);
      }
  }

  // epilogue
  float s1[4][4], s2[4][4];
#pragma unroll
  for (int rt = 0; rt < 4; ++rt)
#pragma unroll
    for (int q = 0; q < 4; ++q) { s1[rt][q] = 0.f; s2[rt][q] = 0.f; }
#pragma unroll
  for (int rt = 0; rt < 4; ++rt)
#pragma unroll
    for (int ct = 0; ct < 4; ++ct) {
      const float bb = b2s[wcc * 64 + ct * 16 + lr];
#pragma unroll
      for (int q = 0; q < 4; ++q) {
        float v = acc2[rt][ct][q] + bb;
        acc2[rt][ct][q] = v;
        s1[rt][q] += v;
        s2[rt][q] += v * v;
      }
    }
#pragma unroll
  for (int m = 1; m < 16; m <<= 1) {
#pragma unroll
    for (int rt = 0; rt < 4; ++rt)
#pragma unroll
      for (int q = 0; q < 4; ++q) {
        s1[rt][q] += __shfl_xor(s1[rt][q], m);
        s2[rt][q] += __shfl_xor(s2[rt][q], m);
      }
  }
  __syncthreads();
  {
    const int rt = lr >> 2, q = lr & 3;
    const int rr = wr * 64 + rt * 16 + lg * 4 + q;
    sumL[wcc][rr] = s1[rt][q];
    sqL[wcc][rr]  = s2[rt][q];
  }
  __syncthreads();
  if (t < 128) {
    const float tot = sumL[0][t] + sumL[1][t];
    const float tsq = sqL[0][t] + sqL[1][t];
    const float mu  = tot * (1.0f / 128.0f);
    const float var = tsq * (1.0f / 128.0f) - mu * mu;
    muL[t] = mu;
    rsL[t] = rsqrtf(var + 1e-5f);
  }
  __syncthreads();

#pragma unroll
  for (int rt = 0; rt < 4; ++rt) {
#pragma unroll
    for (int q = 0; q < 4; ++q) {
      const int rr = wr * 64 + rt * 16 + lg * 4 + q;
      const int grow = row0 + rr;
      if (grow < P.nRows) {
        const float mu = muL[rr], rs = rsL[rr];
        const float* rin = P.attrIn + (size_t)grow * LDIM;
        float* rout = P.attrOut + (size_t)grow * LDIM;
        short* xbo  = P.xbOut + (size_t)grow * LDIM;
#pragma unroll
        for (int ct = 0; ct < 4; ++ct) {
          const int cc = wcc * 64 + ct * 16 + lr;
          const float o = gs[cc] * (acc2[rt][ct][q] - mu) * rs + bes[cc] + rin[cc];
          rout[cc] = o;
          xbo[cc] = f2b(o);
        }
      }
    }
  }
}

// ---- prep kernels ----
__global__ void prep_weights(const float* w1a, const float* w1b, const float* w1c,
                             const float* w2a, const float* w2b, const float* w2c,
                             short* w1h, short* w2h, short* w2l) {
  int i = blockIdx.x * 256 + threadIdx.x;
  constexpr int N1 = 18 * 128 * 384;
  constexpr int N2 = 18 * 128 * 128;
  if (i < N1) {
    int g = i / (128 * 384);
    int rem = i - g * (128 * 384);
    int n = rem / 384, k = rem - n * 384;
    int m = g / 6, s = g - m * 6;
    const float* src = (m == 0) ? w1a : (m == 1) ? w1b : w1c;
    w1h[i] = f2b(src[(size_t)s * (384 * 128) + (size_t)k * 128 + n]);
  } else if (i < N1 + N2) {
    int j = i - N1;
    int g = j / (128 * 128);
    int rem = j - g * (128 * 128);
    int n = rem / 128, k = rem - n * 128;
    int m = g / 6, s = g - m * 6;
    const float* src = (m == 0) ? w2a : (m == 1) ? w2b : w2c;
    float f = src[(size_t)s * (128 * 128) + (size_t)k * 128 + n];
    short hi = f2b(f);
    w2h[j] = hi;
    w2l[j] = f2b(f - b2f(hi));
  }
}

__global__ void prep_xb(const float* x, short* xb) {
  int i = blockIdx.x * 256 + threadIdx.x;
  if (i < NNODE * LDIM) xb[i] = f2b(x[i]);
}

__global__ void prep_deg(const int* mr, const int* wrcv, int* degm, int* degw) {
  int i = blockIdx.x * 256 + threadIdx.x;
  if (i < EM_N) atomicAdd(&degm[mr[i]], 1);
  else if (i < EM_N + EW_N) atomicAdd(&degw[wrcv[i - EM_N]], 1);
}

__global__ void prep_scan(const int* degm, const int* degw, int* moff, int* woff) {
  __shared__ int part[256];
  const int t = threadIdx.x;
  constexpr int NPT = (NNODE + 255) / 256;
#pragma unroll 1
  for (int pass = 0; pass < 2; ++pass) {
    const int* deg = pass == 0 ? degm : degw;
    int* off = pass == 0 ? moff : woff;
    int s = 0;
    for (int i = 0; i < NPT; ++i) {
      int n = t * NPT + i;
      if (n < NNODE) s += deg[n];
    }
    part[t] = s;
    __syncthreads();
    for (int d = 1; d < 256; d <<= 1) {
      int v = (t >= d) ? part[t - d] : 0;
      __syncthreads();
      part[t] += v;
      __syncthreads();
    }
    int base = (t == 0) ? 0 : part[t - 1];
    for (int i = 0; i < NPT; ++i) {
      int n = t * NPT + i;
      if (n < NNODE) { off[n] = base; base += deg[n]; }
    }
    if (t == 255) off[NNODE] = base;
    __syncthreads();
  }
}

__global__ void prep_fill(const int* ms, const int* mr, const int* wsnd, const int* wrcv,
                          const int* moff, const int* woff,
                          int* mcur, int* wcur, int* mcsr, int* wcsr,
                          int* psm, int* pdm, int* psw, int* pdw) {
  int i = blockIdx.x * 256 + threadIdx.x;
  if (i < EM_N) {
    int d = mr[i];
    int pos = moff[d] + atomicAdd(&mcur[d], 1);
    mcsr[pos] = i;
    psm[pos] = ms[i];
    pdm[pos] = d;
  } else if (i < EM_N + EW_N) {
    int j = i - EM_N;
    int d = wrcv[j];
    int pos = woff[d] + atomicAdd(&wcur[d], 1);
    wcsr[pos] = j;
    psw[pos] = wsnd[j];
    pdw[pos] = d;
  }
}

// permute edge attrs into dst-sorted layout (float4 granularity)
__global__ void prep_permute(const float* src_m, const float* src_w,
                             const int* mcsr, const int* wcsr,
                             float* dst_m, float* dst_w) {
  long i = (long)blockIdx.x * 256 + threadIdx.x;
  const long NM4 = (long)EM_N * 32, NW4 = (long)EW_N * 32;
  if (i < NM4) {
    long pos = i >> 5, c = i & 31;
    ((float4*)dst_m)[pos * 32 + c] = ((const float4*)src_m)[(size_t)mcsr[pos] * 32 + c];
  } else if (i < NM4 + NW4) {
    long j = i - NM4;
    long pos = j >> 5, c = j & 31;
    ((float4*)dst_w)[pos * 32 + c] = ((const float4*)src_w)[(size_t)wcsr[pos] * 32 + c];
  }
}

extern "C" void kernel_launch(void* const* d_in, const int* in_sizes, int n_in,
                              void* d_out, int out_size, void* d_ws, size_t ws_size,
                              hipStream_t stream) {
  (void)in_sizes; (void)n_in; (void)out_size;
  const float* x_in   = (const float*)d_in[0];
  const float* mea_in = (const float*)d_in[1];
  const float* wea_in = (const float*)d_in[2];
  const int*   mei    = (const int*)d_in[3];
  const int*   wei    = (const int*)d_in[4];
  const float* W1s[3] = { (const float*)d_in[5],  (const float*)d_in[11], (const float*)d_in[17] };
  const float* B1s[3] = { (const float*)d_in[6],  (const float*)d_in[12], (const float*)d_in[18] };
  const float* W2s[3] = { (const float*)d_in[7],  (const float*)d_in[13], (const float*)d_in[19] };
  const float* B2s[3] = { (const float*)d_in[8],  (const float*)d_in[14], (const float*)d_in[20] };
  const float* Gs[3]  = { (const float*)d_in[9],  (const float*)d_in[15], (const float*)d_in[21] };
  const float* Be[3]  = { (const float*)d_in[10], (const float*)d_in[16], (const float*)d_in[22] };

  float* xo  = (float*)d_out;
  float* meo = xo  + (size_t)NNODE * LDIM;
  float* weo = meo + (size_t)EM_N * LDIM;

  // ws budget: sorted mode needs msort+wsort (64 MB) + ~10 MB small
  const size_t SORT_BYTES = ((size_t)EM_N + EW_N) * LDIM * 4;
  const size_t SMALL_BYTES = (size_t)20 * 1024 * 1024;
  const bool SORTED = ws_size >= SORT_BYTES + SMALL_BYTES;

  float* msort = (float*)d_ws;
  float* wsort = msort + (size_t)EM_N * LDIM;
  short* w1h = SORTED ? (short*)(wsort + (size_t)EW_N * LDIM) : (short*)d_ws;
  short* w2h = w1h + (size_t)18 * 128 * 384;
  short* w2l = w2h + (size_t)18 * 128 * 128;
  short* xb  = w2l + (size_t)18 * 128 * 128;
  int* degm = (int*)(xb + (size_t)NNODE * LDIM);
  int* degw = degm + NNODE;
  int* mcur = degw + NNODE;
  int* wcur = mcur + NNODE;
  int* moff = wcur + NNODE;
  int* woff = moff + (NNODE + 1);
  int* mcsr = woff + (NNODE + 1);
  int* wcsr = mcsr + EM_N;
  int* psm  = wcsr + EW_N;
  int* pdm  = psm + EM_N;
  int* psw  = pdm + EM_N;
  int* pdw  = psw + EW_N;

  hipMemsetAsync(degm, 0, (size_t)4 * NNODE * 4, stream);  // degm,degw,mcur,wcur

  {
    int tot = 18 * 128 * 384 + 18 * 128 * 128;
    prep_weights<<<dim3((tot + 255) / 256), 256, 0, stream>>>(
        W1s[0], W1s[1], W1s[2], W2s[0], W2s[1], W2s[2], w1h, w2h, w2l);
  }
  prep_xb<<<dim3((NNODE * LDIM + 255) / 256), 256, 0, stream>>>(x_in, xb);
  prep_deg<<<dim3((EM_N + EW_N + 255) / 256), 256, 0, stream>>>(mei + EM_N, wei + EW_N, degm, degw);
  prep_scan<<<dim3(1), 256, 0, stream>>>(degm, degw, moff, woff);
  prep_fill<<<dim3((EM_N + EW_N + 255) / 256), 256, 0, stream>>>(
      mei, mei + EM_N, wei, wei + EW_N, moff, woff, mcur, wcur, mcsr, wcsr,
      psm, pdm, psw, pdw);
  if (SORTED) {
    long tot4 = ((long)EM_N + EW_N) * 32;
    prep_permute<<<dim3((unsigned)((tot4 + 255) / 256)), 256, 0, stream>>>(
        mea_in, wea_in, mcsr, wcsr, msort, wsort);
  }

  const int MB = (EM_N + 127) / 128;   // 782
  const int WB = (EW_N + 127) / 128;   // 196
  const int NB = (NNODE + 127) / 128;  // 157

  const float* mc = mea_in;
  const float* wc = wea_in;
  const float* xc = x_in;

  for (int s = 0; s < NSTEP; ++s) {
    MlpParams pm{}, pw{}, pn{};
    const bool last = (s == NSTEP - 1);

    pm.xb = xb;
    pm.W1H = w1h + (size_t)(0 * 6 + s) * 128 * 384;
    pm.W2H = w2h + (size_t)(0 * 6 + s) * 128 * 128;
    pm.W2L = w2l + (size_t)(0 * 6 + s) * 128 * 128;
    pm.b1 = B1s[0] + s * LDIM; pm.b2 = B2s[0] + s * LDIM;
    pm.gam = Gs[0] + s * LDIM; pm.bet = Be[0] + s * LDIM;
    pm.nRows = EM_N;

    pw.xb = xb;
    pw.W1H = w1h + (size_t)(1 * 6 + s) * 128 * 384;
    pw.W2H = w2h + (size_t)(1 * 6 + s) * 128 * 128;
    pw.W2L = w2l + (size_t)(1 * 6 + s) * 128 * 128;
    pw.b1 = B1s[1] + s * LDIM; pw.b2 = B2s[1] + s * LDIM;
    pw.gam = Gs[1] + s * LDIM; pw.bet = Be[1] + s * LDIM;
    pw.nRows = EW_N;

    if (SORTED) {
      pm.attrIn = msort; pm.attrOut = msort;
      pm.src = psm; pm.dst = pdm;
      pm.oidx = mcsr; pm.origOut = last ? meo : nullptr;
      pw.attrIn = wsort; pw.attrOut = wsort;
      pw.src = psw; pw.dst = pdw;
      pw.oidx = wcsr; pw.origOut = last ? weo : nullptr;
    } else {
      pm.attrIn = mc; pm.attrOut = meo;
      pm.src = mei; pm.dst = mei + EM_N;
      pw.attrIn = wc; pw.attrOut = weo;
      pw.src = wei; pw.dst = wei + EW_N;
    }

    edge_kernel<<<dim3(MB + WB), 256, 0, stream>>>(pm, pw, MB);

    pn.xb = xb; pn.attrIn = xc; pn.attrOut = xo; pn.xbOut = xb;
    pn.off1 = moff; pn.off2 = woff;
    pn.W1H = w1h + (size_t)(2 * 6 + s) * 128 * 384;
    pn.W2H = w2h + (size_t)(2 * 6 + s) * 128 * 128;
    pn.W2L = w2l + (size_t)(2 * 6 + s) * 128 * 128;
    pn.b1 = B1s[2] + s * LDIM; pn.b2 = B2s[2] + s * LDIM;
    pn.gam = Gs[2] + s * LDIM; pn.bet = Be[2] + s * LDIM;
    pn.nRows = NNODE;

    if (SORTED) {
      pn.gsrc1 = msort; pn.gsrc2 = wsort;
      node_kernel<true><<<dim3(NB), 256, 0, stream>>>(pn);
    } else {
      pn.gsrc1 = meo; pn.gsrc2 = weo;
      pn.csr1 = mcsr; pn.csr2 = wcsr;
      node_kernel<false><<<dim3(NB), 256, 0, stream>>>(pn);
    }

    mc = meo; wc = weo; xc = xo;
  }
}

// Round 15
// 805.721 us; speedup vs baseline: 1.2826x; 1.0580x over previous
//
#include <hip/hip_runtime.h>

constexpr int LDIM  = 128;
constexpr int NNODE = 20000;
constexpr int EM_N  = 100000;
constexpr int EW_N  = 25000;
constexpr int NSTEP = 6;

typedef short bf16x8 __attribute__((ext_vector_type(8)));
typedef short bf16x4 __attribute__((ext_vector_type(4)));
typedef float f32x4  __attribute__((ext_vector_type(4)));

struct MlpParams {
  const short* xb;      // bf16 node features (gather source)
  const float* attrIn;  // residual input (f32)
  float*       attrOut;
  short*       xbOut;   // node: bf16 copy of new x
  const int*   src;
  const int*   dst;
  const int*   oidx;    // edge, last step: sorted pos -> original edge id
  float*       origOut; // edge, last step: d_out region (original order)
  const float* gsrc1;   // node: mesh edge attr (gather source)
  const float* gsrc2;   // node: world edge attr
  const int*   off1;    // node: mesh CSR offsets [NNODE+1]
  const int*   csr1;    // node: mesh CSR edge ids (CSR mode only)
  const int*   off2;
  const int*   csr2;
  const short* W1H;     // bf16 [128 n][384 k]
  const short* W2H;     // bf16 hi [128 n][128 k]
  const short* W2L;     // bf16 lo
  const float* b1;
  const float* b2;
  const float* gam;
  const float* bet;
  int nRows;
};

__device__ __forceinline__ short f2b(float f) {
  unsigned int u = __float_as_uint(f);
  u = (u + 0x7fffu + ((u >> 16) & 1u)) >> 16;
  return (short)u;
}
__device__ __forceinline__ float b2f(short s) {
  return __uint_as_float(((unsigned int)(unsigned short)s) << 16);
}
__device__ __forceinline__ bf16x4 cvt4(float4 a, float sc) {
  bf16x4 o;
  o[0] = f2b(a.x * sc); o[1] = f2b(a.y * sc);
  o[2] = f2b(a.z * sc); o[3] = f2b(a.w * sc);
  return o;
}
__device__ __forceinline__ bf16x4 cvt4v(f32x4 a, float sc) {
  bf16x4 o;
  o[0] = f2b(a[0] * sc); o[1] = f2b(a[1] * sc);
  o[2] = f2b(a[2] * sc); o[3] = f2b(a[3] * sc);
  return o;
}

// ================= EDGE kernel (R14 verbatim) ================================
__launch_bounds__(256, 2)
__global__ void edge_kernel(MlpParams pmA, MlpParams pmB, int blocksA) {
  const bool isA = (int)blockIdx.x < blocksA;
  const MlpParams P = isA ? pmA : pmB;
  const int bid  = isA ? (int)blockIdx.x : (int)blockIdx.x - blocksA;
  const int row0 = bid * 128;

  __shared__ __align__(16) short Abuf[128][40];
  __shared__ __align__(16) short Bhi[128][40];
  __shared__ __align__(16) short Blo[128][40];
  __shared__ __align__(16) short Hbuf[128][136];
  __shared__ float b1s[128], b2s[128], gs[128], bes[128];
  __shared__ int   idxa[128], idxb[128];
  __shared__ float sumL[2][128], sqL[2][128];
  __shared__ float muL[128], rsL[128];

  const int t = threadIdx.x;

  if (t < 128) {
    b1s[t] = P.b1[t];
    gs[t]  = P.gam[t];
    int r = row0 + t;
    idxa[t] = (r < P.nRows) ? P.src[r] : 0;
  } else {
    int t2 = t - 128;
    b2s[t2] = P.b2[t2];
    bes[t2] = P.bet[t2];
    int r = row0 + t2;
    idxb[t2] = (r < P.nRows) ? P.dst[r] : 0;
  }
  __syncthreads();

  const int l   = t & 63;
  const int wid = t >> 6;
  const int wr  = wid >> 1, wcc = wid & 1;
  const int lr  = l & 15,  lg  = l >> 4;

  const int  srow  = t >> 1, sh = t & 1;
  const int  sgRow = row0 + srow;
  const bool sval  = sgRow < P.nRows;
  const int  sgC   = sval ? sgRow : 0;
  const float vmask = sval ? 1.f : 0.f;

  const short* bx0   = P.xb + (size_t)idxa[srow] * LDIM + sh * 16;
  const short* bx1   = P.xb + (size_t)idxb[srow] * LDIM + sh * 16;
  const float* base2 = P.attrIn + (size_t)sgC * LDIM + sh * 16;

  const int wrow = t >> 1, wsh = t & 1;
  const short* w1base = P.W1H + (size_t)wrow * 384 + wsh * 16;

  f32x4 acc[4][4];
#pragma unroll
  for (int i = 0; i < 4; ++i)
#pragma unroll
    for (int j = 0; j < 4; ++j) acc[i][j] = f32x4{0.f, 0.f, 0.f, 0.f};

  const bf16x8 z8 = {0, 0, 0, 0, 0, 0, 0, 0};
  bf16x8 pB0, pB1;
  float4 pA0, pA1, pA2, pA3;
  bf16x8 pW0, pW1;
  {
    pB0 = *(const bf16x8*)bx0;
    pB1 = *(const bf16x8*)(bx0 + 8);
    pW0 = *(const bf16x8*)w1base;
    pW1 = *(const bf16x8*)(w1base + 8);
  }

  // phase 1
#pragma unroll
  for (int kc = 0; kc < 12; ++kc) {
    const int seg = kc >> 2;
    if (kc > 0) __syncthreads();
    {
      if (seg < 2) {
        *(bf16x8*)&Abuf[srow][sh * 16]     = sval ? pB0 : z8;
        *(bf16x8*)&Abuf[srow][sh * 16 + 8] = sval ? pB1 : z8;
      } else {
        *(bf16x4*)&Abuf[srow][sh * 16 + 0]  = cvt4(pA0, vmask);
        *(bf16x4*)&Abuf[srow][sh * 16 + 4]  = cvt4(pA1, vmask);
        *(bf16x4*)&Abuf[srow][sh * 16 + 8]  = cvt4(pA2, vmask);
        *(bf16x4*)&Abuf[srow][sh * 16 + 12] = cvt4(pA3, vmask);
      }
      *(bf16x8*)&Bhi[wrow][wsh * 16]     = pW0;
      *(bf16x8*)&Bhi[wrow][wsh * 16 + 8] = pW1;
    }
    __syncthreads();
    if (kc < 11) {
      const int kn = kc + 1, segn = kn >> 2, partn = kn & 3;
      if (segn == 0) {
        pB0 = *(const bf16x8*)(bx0 + partn * 32);
        pB1 = *(const bf16x8*)(bx0 + partn * 32 + 8);
      } else if (segn == 1) {
        pB0 = *(const bf16x8*)(bx1 + partn * 32);
        pB1 = *(const bf16x8*)(bx1 + partn * 32 + 8);
      } else {
        const float4* bp = (const float4*)(base2 + partn * 32);
        pA0 = bp[0]; pA1 = bp[1]; pA2 = bp[2]; pA3 = bp[3];
      }
      pW0 = *(const bf16x8*)(w1base + kn * 32);
      pW1 = *(const bf16x8*)(w1base + kn * 32 + 8);
    }
    bf16x8 av[4], bh[4];
#pragma unroll
    for (int mi = 0; mi < 4; ++mi)
      av[mi] = *(const bf16x8*)&Abuf[wr * 64 + mi * 16 + lr][lg * 8];
#pragma unroll
    for (int ni = 0; ni < 4; ++ni)
      bh[ni] = *(const bf16x8*)&Bhi[wcc * 64 + ni * 16 + lr][lg * 8];
#pragma unroll
    for (int mi = 0; mi < 4; ++mi)
#pragma unroll
      for (int ni = 0; ni < 4; ++ni)
        acc[mi][ni] = __builtin_amdgcn_mfma_f32_16x16x32_bf16(av[mi], bh[ni], acc[mi][ni], 0, 0, 0);
  }

  // H write (acc dies)
#pragma unroll
  for (int rt = 0; rt < 4; ++rt)
#pragma unroll
    for (int ct = 0; ct < 4; ++ct) {
      const int cc = wcc * 64 + ct * 16 + lr;
      const float bb = b1s[cc];
#pragma unroll
      for (int q = 0; q < 4; ++q) {
        const int rr = wr * 64 + rt * 16 + lg * 4 + q;
        Hbuf[rr][cc] = f2b(fmaxf(acc[rt][ct][q] + bb, 0.f));
      }
    }

  // phase 2 (W2 hi/lo, prefetched)
  f32x4 acc2[4][4];
#pragma unroll
  for (int i = 0; i < 4; ++i)
#pragma unroll
    for (int j = 0; j < 4; ++j) acc2[i][j] = f32x4{0.f, 0.f, 0.f, 0.f};

  const short* w2hbase = P.W2H + (size_t)wrow * 128 + wsh * 16;
  const short* w2lbase = P.W2L + (size_t)wrow * 128 + wsh * 16;

  bf16x8 qh0 = *(const bf16x8*)w2hbase;
  bf16x8 qh1 = *(const bf16x8*)(w2hbase + 8);
  bf16x8 ql0 = *(const bf16x8*)w2lbase;
  bf16x8 ql1 = *(const bf16x8*)(w2lbase + 8);

#pragma unroll
  for (int kc = 0; kc < 4; ++kc) {
    __syncthreads();
    {
      *(bf16x8*)&Bhi[wrow][wsh * 16]     = qh0;
      *(bf16x8*)&Bhi[wrow][wsh * 16 + 8] = qh1;
      *(bf16x8*)&Blo[wrow][wsh * 16]     = ql0;
      *(bf16x8*)&Blo[wrow][wsh * 16 + 8] = ql1;
    }
    __syncthreads();
    if (kc < 3) {
      qh0 = *(const bf16x8*)(w2hbase + (kc + 1) * 32);
      qh1 = *(const bf16x8*)(w2hbase + (kc + 1) * 32 + 8);
      ql0 = *(const bf16x8*)(w2lbase + (kc + 1) * 32);
      ql1 = *(const bf16x8*)(w2lbase + (kc + 1) * 32 + 8);
    }
    bf16x8 av2[4], bh2[4], bl2[4];
#pragma unroll
    for (int rt = 0; rt < 4; ++rt)
      av2[rt] = *(const bf16x8*)&Hbuf[wr * 64 + rt * 16 + lr][kc * 32 + lg * 8];
#pragma unroll
    for (int ct = 0; ct < 4; ++ct) {
      bh2[ct] = *(const bf16x8*)&Bhi[wcc * 64 + ct * 16 + lr][lg * 8];
      bl2[ct] = *(const bf16x8*)&Blo[wcc * 64 + ct * 16 + lr][lg * 8];
    }
#pragma unroll
    for (int rt = 0; rt < 4; ++rt)
#pragma unroll
      for (int ct = 0; ct < 4; ++ct) {
        acc2[rt][ct] = __builtin_amdgcn_mfma_f32_16x16x32_bf16(av2[rt], bl2[ct], acc2[rt][ct], 0, 0, 0);
        acc2[rt][ct] = __builtin_amdgcn_mfma_f32_16x16x32_bf16(av2[rt], bh2[ct], acc2[rt][ct], 0, 0, 0);
      }
  }

  // epilogue
  float s1[4][4], s2[4][4];
#pragma unroll
  for (int rt = 0; rt < 4; ++rt)
#pragma unroll
    for (int q = 0; q < 4; ++q) { s1[rt][q] = 0.f; s2[rt][q] = 0.f; }
#pragma unroll
  for (int rt = 0; rt < 4; ++rt)
#pragma unroll
    for (int ct = 0; ct < 4; ++ct) {
      const float bb = b2s[wcc * 64 + ct * 16 + lr];
#pragma unroll
      for (int q = 0; q < 4; ++q) {
        float v = acc2[rt][ct][q] + bb;
        acc2[rt][ct][q] = v;
        s1[rt][q] += v;
        s2[rt][q] += v * v;
      }
    }
#pragma unroll
  for (int m = 1; m < 16; m <<= 1) {
#pragma unroll
    for (int rt = 0; rt < 4; ++rt)
#pragma unroll
      for (int q = 0; q < 4; ++q) {
        s1[rt][q] += __shfl_xor(s1[rt][q], m);
        s2[rt][q] += __shfl_xor(s2[rt][q], m);
      }
  }
  __syncthreads();
  {
    const int rt = lr >> 2, q = lr & 3;
    const int rr = wr * 64 + rt * 16 + lg * 4 + q;
    sumL[wcc][rr] = s1[rt][q];
    sqL[wcc][rr]  = s2[rt][q];
  }
  __syncthreads();
  if (t < 128) {
    const float tot = sumL[0][t] + sumL[1][t];
    const float tsq = sqL[0][t] + sqL[1][t];
    const float mu  = tot * (1.0f / 128.0f);
    const float var = tsq * (1.0f / 128.0f) - mu * mu;
    muL[t] = mu;
    rsL[t] = rsqrtf(var + 1e-5f);
  }
  __syncthreads();

#pragma unroll
  for (int rt = 0; rt < 4; ++rt) {
#pragma unroll
    for (int q = 0; q < 4; ++q) {
      const int rr = wr * 64 + rt * 16 + lg * 4 + q;
      const int grow = row0 + rr;
      if (grow < P.nRows) {
        const float mu = muL[rr], rs = rsL[rr];
        const float* rin = P.attrIn + (size_t)grow * LDIM;
        float* rout = P.attrOut + (size_t)grow * LDIM;
        float* rout2 = nullptr;
        if (P.origOut) rout2 = P.origOut + (size_t)P.oidx[grow] * LDIM;
#pragma unroll
        for (int ct = 0; ct < 4; ++ct) {
          const int cc = wcc * 64 + ct * 16 + lr;
          const float o = gs[cc] * (acc2[rt][ct][q] - mu) * rs + bes[cc] + rin[cc];
          rout[cc] = o;
          if (rout2) rout2[cc] = o;
        }
      }
    }
  }
}

// ============ NODE kernel: BR=32, 4 waves of 32x32 tiles (625 blocks) =======
template<bool CONTIG>
__launch_bounds__(256, 3)
__global__ void node_kernel(MlpParams P) {
  constexpr int BR = 32;
  const int row0 = (int)blockIdx.x * BR;

  __shared__ __align__(16) short Abuf[BR][40];
  __shared__ __align__(16) short Bhi[128][40];
  __shared__ __align__(16) short Blo[128][40];
  __shared__ __align__(16) short Hbuf[BR][136];
  __shared__ float b1s[128], b2s[128], gs[128], bes[128];
  __shared__ float sumL[4][BR], sqL[4][BR], muL[BR], rsL[BR];

  const int t = threadIdx.x;
  if (t < 128) { b1s[t] = P.b1[t]; gs[t] = P.gam[t]; }
  else         { b2s[t - 128] = P.b2[t - 128]; bes[t - 128] = P.bet[t - 128]; }

  const int l  = t & 63;
  const int w  = t >> 6;        // wave -> cols w*32..w*32+31
  const int lr = l & 15, lg = l >> 4;

  const int  srow  = t >> 3, sh = t & 7;   // 8 threads/row; thread owns cols sh*16..+15
  const int  sgRow = row0 + srow;
  const bool sval  = sgRow < P.nRows;
  const int  sgC   = sval ? sgRow : 0;
  const int  myPart = sh >> 1, myHalf = sh & 1;

  const int wrow = t >> 1, wsh = t & 1;    // W staging: 2 threads/row over 128 n
  const short* w1base = P.W1H + (size_t)wrow * 384 + wsh * 16;
  const short* xrow   = P.xb + (size_t)sgC * LDIM + sh * 16;
  const bf16x8 z8 = {0, 0, 0, 0, 0, 0, 0, 0};

  f32x4 acc[2][2];
#pragma unroll
  for (int i = 0; i < 2; ++i)
#pragma unroll
    for (int j = 0; j < 2; ++j) acc[i][j] = f32x4{0.f, 0.f, 0.f, 0.f};

  // hoisted MESH gather: thread accumulates its 16 cols over the contiguous run
  f32x4 g[4];
#pragma unroll
  for (int j = 0; j < 4; ++j) g[j] = f32x4{0.f, 0.f, 0.f, 0.f};
  float scm = 1.f;
  {
    int beg = 0, end = 0;
    if (sval) { beg = P.off1[sgRow]; end = P.off1[sgRow + 1]; }
    for (int i = beg; i < end; ++i) {
      const size_t r = CONTIG ? (size_t)i : (size_t)P.csr1[i];
      const f32x4* p = (const f32x4*)(P.gsrc1 + r * LDIM + sh * 16);
#pragma unroll
      for (int j = 0; j < 4; ++j) g[j] += p[j];
    }
    scm = 1.0f / (float)max(end - beg, 1);
  }

  __syncthreads();

  float scw = 1.f;
#pragma unroll
  for (int kc = 0; kc < 12; ++kc) {
    const int seg = kc >> 2, part = kc & 3;
    if (kc > 0) __syncthreads();
    {
      if (myPart == part) {            // this thread owns 16 of this chunk's 32 cols
        if (seg == 0) {
          const bf16x8* xp = (const bf16x8*)xrow;
          *(bf16x8*)&Abuf[srow][myHalf * 16]     = sval ? xp[0] : z8;
          *(bf16x8*)&Abuf[srow][myHalf * 16 + 8] = sval ? xp[1] : z8;
        } else {
          const float sc = (seg == 1) ? scm : scw;
          *(bf16x4*)&Abuf[srow][myHalf * 16 + 0]  = cvt4v(g[0], sc);
          *(bf16x4*)&Abuf[srow][myHalf * 16 + 4]  = cvt4v(g[1], sc);
          *(bf16x4*)&Abuf[srow][myHalf * 16 + 8]  = cvt4v(g[2], sc);
          *(bf16x4*)&Abuf[srow][myHalf * 16 + 12] = cvt4v(g[3], sc);
        }
      }
      const short* wsrc = w1base + kc * 32;
      *(bf16x8*)&Bhi[wrow][wsh * 16]     = *(const bf16x8*)wsrc;
      *(bf16x8*)&Bhi[wrow][wsh * 16 + 8] = *(const bf16x8*)(wsrc + 8);
      if (kc == 7) {
        // mesh g consumed (kc 4-7): reuse for WORLD gather (feeds kc 8-11)
#pragma unroll
        for (int j = 0; j < 4; ++j) g[j] = f32x4{0.f, 0.f, 0.f, 0.f};
        int beg = 0, end = 0;
        if (sval) { beg = P.off2[sgRow]; end = P.off2[sgRow + 1]; }
        for (int i = beg; i < end; ++i) {
          const size_t r = CONTIG ? (size_t)i : (size_t)P.csr2[i];
          const f32x4* p = (const f32x4*)(P.gsrc2 + r * LDIM + sh * 16);
#pragma unroll
          for (int j = 0; j < 4; ++j) g[j] += p[j];
        }
        scw = 1.0f / (float)max(end - beg, 1);
      }
    }
    __syncthreads();
    bf16x8 av[2], bh[2];
#pragma unroll
    for (int mi = 0; mi < 2; ++mi)
      av[mi] = *(const bf16x8*)&Abuf[mi * 16 + lr][lg * 8];
#pragma unroll
    for (int ni = 0; ni < 2; ++ni)
      bh[ni] = *(const bf16x8*)&Bhi[w * 32 + ni * 16 + lr][lg * 8];
#pragma unroll
    for (int mi = 0; mi < 2; ++mi)
#pragma unroll
      for (int ni = 0; ni < 2; ++ni)
        acc[mi][ni] = __builtin_amdgcn_mfma_f32_16x16x32_bf16(av[mi], bh[ni], acc[mi][ni], 0, 0, 0);
  }

  // H write (acc dies): rows rr = mi*16+lg*4+q, cols cc = w*32+ni*16+lr
#pragma unroll
  for (int mi = 0; mi < 2; ++mi)
#pragma unroll
    for (int ni = 0; ni < 2; ++ni) {
      const int cc = w * 32 + ni * 16 + lr;
      const float bb = b1s[cc];
#pragma unroll
      for (int q = 0; q < 4; ++q) {
        const int rr = mi * 16 + lg * 4 + q;
        Hbuf[rr][cc] = f2b(fmaxf(acc[mi][ni][q] + bb, 0.f));
      }
    }

  // phase 2 (W2 hi/lo)
  f32x4 acc2[2][2];
#pragma unroll
  for (int i = 0; i < 2; ++i)
#pragma unroll
    for (int j = 0; j < 2; ++j) acc2[i][j] = f32x4{0.f, 0.f, 0.f, 0.f};

  const short* w2hbase = P.W2H + (size_t)wrow * 128 + wsh * 16;
  const short* w2lbase = P.W2L + (size_t)wrow * 128 + wsh * 16;
  bf16x8 qh0 = *(const bf16x8*)w2hbase;
  bf16x8 qh1 = *(const bf16x8*)(w2hbase + 8);
  bf16x8 ql0 = *(const bf16x8*)w2lbase;
  bf16x8 ql1 = *(const bf16x8*)(w2lbase + 8);

#pragma unroll
  for (int kc = 0; kc < 4; ++kc) {
    __syncthreads();
    {
      *(bf16x8*)&Bhi[wrow][wsh * 16]     = qh0;
      *(bf16x8*)&Bhi[wrow][wsh * 16 + 8] = qh1;
      *(bf16x8*)&Blo[wrow][wsh * 16]     = ql0;
      *(bf16x8*)&Blo[wrow][wsh * 16 + 8] = ql1;
    }
    __syncthreads();
    if (kc < 3) {
      qh0 = *(const bf16x8*)(w2hbase + (kc + 1) * 32);
      qh1 = *(const bf16x8*)(w2hbase + (kc + 1) * 32 + 8);
      ql0 = *(const bf16x8*)(w2lbase + (kc + 1) * 32);
      ql1 = *(const bf16x8*)(w2lbase + (kc + 1) * 32 + 8);
    }
    bf16x8 av2[2], bh2[2], bl2[2];
#pragma unroll
    for (int mi = 0; mi < 2; ++mi)
      av2[mi] = *(const bf16x8*)&Hbuf[mi * 16 + lr][kc * 32 + lg * 8];
#pragma unroll
    for (int ni = 0; ni < 2; ++ni) {
      bh2[ni] = *(const bf16x8*)&Bhi[w * 32 + ni * 16 + lr][lg * 8];
      bl2[ni] = *(const bf16x8*)&Blo[w * 32 + ni * 16 + lr][lg * 8];
    }
#pragma unroll
    for (int mi = 0; mi < 2; ++mi)
#pragma unroll
      for (int ni = 0; ni < 2; ++ni) {
        acc2[mi][ni] = __builtin_amdgcn_mfma_f32_16x16x32_bf16(av2[mi], bl2[ni], acc2[mi][ni], 0, 0, 0);
        acc2[mi][ni] = __builtin_amdgcn_mfma_f32_16x16x32_bf16(av2[mi], bh2[ni], acc2[mi][ni], 0, 0, 0);
      }
  }

  // epilogue: b2 + LN stats
  float s1[2][4], s2[2][4];
#pragma unroll
  for (int mi = 0; mi < 2; ++mi)
#pragma unroll
    for (int q = 0; q < 4; ++q) { s1[mi][q] = 0.f; s2[mi][q] = 0.f; }
#pragma unroll
  for (int mi = 0; mi < 2; ++mi)
#pragma unroll
    for (int ni = 0; ni < 2; ++ni) {
      const float bb = b2s[w * 32 + ni * 16 + lr];
#pragma unroll
      for (int q = 0; q < 4; ++q) {
        float v = acc2[mi][ni][q] + bb;
        acc2[mi][ni][q] = v;
        s1[mi][q] += v;
        s2[mi][q] += v * v;
      }
    }
#pragma unroll
  for (int m = 1; m < 16; m <<= 1) {
#pragma unroll
    for (int mi = 0; mi < 2; ++mi)
#pragma unroll
      for (int q = 0; q < 4; ++q) {
        s1[mi][q] += __shfl_xor(s1[mi][q], m);
        s2[mi][q] += __shfl_xor(s2[mi][q], m);
      }
  }
  __syncthreads();
  if (lr < 8) {
    const int mi = lr >> 2, q = lr & 3;
    const int rr = mi * 16 + lg * 4 + q;
    sumL[w][rr] = s1[mi][q];
    sqL[w][rr]  = s2[mi][q];
  }
  __syncthreads();
  if (t < BR) {
    float tot = 0.f, tsq = 0.f;
#pragma unroll
    for (int ww = 0; ww < 4; ++ww) { tot += sumL[ww][t]; tsq += sqL[ww][t]; }
    const float mu  = tot * (1.0f / 128.0f);
    const float var = tsq * (1.0f / 128.0f) - mu * mu;
    muL[t] = mu;
    rsL[t] = rsqrtf(var + 1e-5f);
  }
  __syncthreads();

#pragma unroll
  for (int mi = 0; mi < 2; ++mi) {
#pragma unroll
    for (int q = 0; q < 4; ++q) {
      const int rr = mi * 16 + lg * 4 + q;
      const int grow = row0 + rr;
      if (grow < P.nRows) {
        const float mu = muL[rr], rs = rsL[rr];
        const float* rin = P.attrIn + (size_t)grow * LDIM;
        float* rout = P.attrOut + (size_t)grow * LDIM;
        short* xbo  = P.xbOut + (size_t)grow * LDIM;
#pragma unroll
        for (int ni = 0; ni < 2; ++ni) {
          const int cc = w * 32 + ni * 16 + lr;
          const float o = gs[cc] * (acc2[mi][ni][q] - mu) * rs + bes[cc] + rin[cc];
          rout[cc] = o;
          xbo[cc] = f2b(o);
        }
      }
    }
  }
}

// ---- prep kernels ----
__global__ void prep_weights(const float* w1a, const float* w1b, const float* w1c,
                             const float* w2a, const float* w2b, const float* w2c,
                             short* w1h, short* w2h, short* w2l) {
  int i = blockIdx.x * 256 + threadIdx.x;
  constexpr int N1 = 18 * 128 * 384;
  constexpr int N2 = 18 * 128 * 128;
  if (i < N1) {
    int g = i / (128 * 384);
    int rem = i - g * (128 * 384);
    int n = rem / 384, k = rem - n * 384;
    int m = g / 6, s = g - m * 6;
    const float* src = (m == 0) ? w1a : (m == 1) ? w1b : w1c;
    w1h[i] = f2b(src[(size_t)s * (384 * 128) + (size_t)k * 128 + n]);
  } else if (i < N1 + N2) {
    int j = i - N1;
    int g = j / (128 * 128);
    int rem = j - g * (128 * 128);
    int n = rem / 128, k = rem - n * 128;
    int m = g / 6, s = g - m * 6;
    const float* src = (m == 0) ? w2a : (m == 1) ? w2b : w2c;
    float f = src[(size_t)s * (128 * 128) + (size_t)k * 128 + n];
    short hi = f2b(f);
    w2h[j] = hi;
    w2l[j] = f2b(f - b2f(hi));
  }
}

__global__ void prep_xb(const float* x, short* xb) {
  int i = blockIdx.x * 256 + threadIdx.x;
  if (i < NNODE * LDIM) xb[i] = f2b(x[i]);
}

__global__ void prep_deg(const int* mr, const int* wrcv, int* degm, int* degw) {
  int i = blockIdx.x * 256 + threadIdx.x;
  if (i < EM_N) atomicAdd(&degm[mr[i]], 1);
  else if (i < EM_N + EW_N) atomicAdd(&degw[wrcv[i - EM_N]], 1);
}

__global__ void prep_scan(const int* degm, const int* degw, int* moff, int* woff) {
  __shared__ int part[256];
  const int t = threadIdx.x;
  constexpr int NPT = (NNODE + 255) / 256;
#pragma unroll 1
  for (int pass = 0; pass < 2; ++pass) {
    const int* deg = pass == 0 ? degm : degw;
    int* off = pass == 0 ? moff : woff;
    int s = 0;
    for (int i = 0; i < NPT; ++i) {
      int n = t * NPT + i;
      if (n < NNODE) s += deg[n];
    }
    part[t] = s;
    __syncthreads();
    for (int d = 1; d < 256; d <<= 1) {
      int v = (t >= d) ? part[t - d] : 0;
      __syncthreads();
      part[t] += v;
      __syncthreads();
    }
    int base = (t == 0) ? 0 : part[t - 1];
    for (int i = 0; i < NPT; ++i) {
      int n = t * NPT + i;
      if (n < NNODE) { off[n] = base; base += deg[n]; }
    }
    if (t == 255) off[NNODE] = base;
    __syncthreads();
  }
}

__global__ void prep_fill(const int* ms, const int* mr, const int* wsnd, const int* wrcv,
                          const int* moff, const int* woff,
                          int* mcur, int* wcur, int* mcsr, int* wcsr,
                          int* psm, int* pdm, int* psw, int* pdw) {
  int i = blockIdx.x * 256 + threadIdx.x;
  if (i < EM_N) {
    int d = mr[i];
    int pos = moff[d] + atomicAdd(&mcur[d], 1);
    mcsr[pos] = i;
    psm[pos] = ms[i];
    pdm[pos] = d;
  } else if (i < EM_N + EW_N) {
    int j = i - EM_N;
    int d = wrcv[j];
    int pos = woff[d] + atomicAdd(&wcur[d], 1);
    wcsr[pos] = j;
    psw[pos] = wsnd[j];
    pdw[pos] = d;
  }
}

__global__ void prep_permute(const float* src_m, const float* src_w,
                             const int* mcsr, const int* wcsr,
                             float* dst_m, float* dst_w) {
  long i = (long)blockIdx.x * 256 + threadIdx.x;
  const long NM4 = (long)EM_N * 32, NW4 = (long)EW_N * 32;
  if (i < NM4) {
    long pos = i >> 5, c = i & 31;
    ((float4*)dst_m)[pos * 32 + c] = ((const float4*)src_m)[(size_t)mcsr[pos] * 32 + c];
  } else if (i < NM4 + NW4) {
    long j = i - NM4;
    long pos = j >> 5, c = j & 31;
    ((float4*)dst_w)[pos * 32 + c] = ((const float4*)src_w)[(size_t)wcsr[pos] * 32 + c];
  }
}

extern "C" void kernel_launch(void* const* d_in, const int* in_sizes, int n_in,
                              void* d_out, int out_size, void* d_ws, size_t ws_size,
                              hipStream_t stream) {
  (void)in_sizes; (void)n_in; (void)out_size;
  const float* x_in   = (const float*)d_in[0];
  const float* mea_in = (const float*)d_in[1];
  const float* wea_in = (const float*)d_in[2];
  const int*   mei    = (const int*)d_in[3];
  const int*   wei    = (const int*)d_in[4];
  const float* W1s[3] = { (const float*)d_in[5],  (const float*)d_in[11], (const float*)d_in[17] };
  const float* B1s[3] = { (const float*)d_in[6],  (const float*)d_in[12], (const float*)d_in[18] };
  const float* W2s[3] = { (const float*)d_in[7],  (const float*)d_in[13], (const float*)d_in[19] };
  const float* B2s[3] = { (const float*)d_in[8],  (const float*)d_in[14], (const float*)d_in[20] };
  const float* Gs[3]  = { (const float*)d_in[9],  (const float*)d_in[15], (const float*)d_in[21] };
  const float* Be[3]  = { (const float*)d_in[10], (const float*)d_in[16], (const float*)d_in[22] };

  float* xo  = (float*)d_out;
  float* meo = xo  + (size_t)NNODE * LDIM;
  float* weo = meo + (size_t)EM_N * LDIM;

  const size_t SORT_BYTES = ((size_t)EM_N + EW_N) * LDIM * 4;
  const size_t SMALL_BYTES = (size_t)20 * 1024 * 1024;
  const bool SORTED = ws_size >= SORT_BYTES + SMALL_BYTES;

  float* msort = (float*)d_ws;
  float* wsort = msort + (size_t)EM_N * LDIM;
  short* w1h = SORTED ? (short*)(wsort + (size_t)EW_N * LDIM) : (short*)d_ws;
  short* w2h = w1h + (size_t)18 * 128 * 384;
  short* w2l = w2h + (size_t)18 * 128 * 128;
  short* xb  = w2l + (size_t)18 * 128 * 128;
  int* degm = (int*)(xb + (size_t)NNODE * LDIM);
  int* degw = degm + NNODE;
  int* mcur = degw + NNODE;
  int* wcur = mcur + NNODE;
  int* moff = wcur + NNODE;
  int* woff = moff + (NNODE + 1);
  int* mcsr = woff + (NNODE + 1);
  int* wcsr = mcsr + EM_N;
  int* psm  = wcsr + EW_N;
  int* pdm  = psm + EM_N;
  int* psw  = pdm + EM_N;
  int* pdw  = psw + EW_N;

  hipMemsetAsync(degm, 0, (size_t)4 * NNODE * 4, stream);

  {
    int tot = 18 * 128 * 384 + 18 * 128 * 128;
    prep_weights<<<dim3((tot + 255) / 256), 256, 0, stream>>>(
        W1s[0], W1s[1], W1s[2], W2s[0], W2s[1], W2s[2], w1h, w2h, w2l);
  }
  prep_xb<<<dim3((NNODE * LDIM + 255) / 256), 256, 0, stream>>>(x_in, xb);
  prep_deg<<<dim3((EM_N + EW_N + 255) / 256), 256, 0, stream>>>(mei + EM_N, wei + EW_N, degm, degw);
  prep_scan<<<dim3(1), 256, 0, stream>>>(degm, degw, moff, woff);
  prep_fill<<<dim3((EM_N + EW_N + 255) / 256), 256, 0, stream>>>(
      mei, mei + EM_N, wei, wei + EW_N, moff, woff, mcur, wcur, mcsr, wcsr,
      psm, pdm, psw, pdw);
  if (SORTED) {
    long tot4 = ((long)EM_N + EW_N) * 32;
    prep_permute<<<dim3((unsigned)((tot4 + 255) / 256)), 256, 0, stream>>>(
        mea_in, wea_in, mcsr, wcsr, msort, wsort);
  }

  const int MB = (EM_N + 127) / 128;   // 782
  const int WB = (EW_N + 127) / 128;   // 196
  const int NB = (NNODE + 31) / 32;    // 625

  const float* mc = mea_in;
  const float* wc = wea_in;
  const float* xc = x_in;

  for (int s = 0; s < NSTEP; ++s) {
    MlpParams pm{}, pw{}, pn{};
    const bool last = (s == NSTEP - 1);

    pm.xb = xb;
    pm.W1H = w1h + (size_t)(0 * 6 + s) * 128 * 384;
    pm.W2H = w2h + (size_t)(0 * 6 + s) * 128 * 128;
    pm.W2L = w2l + (size_t)(0 * 6 + s) * 128 * 128;
    pm.b1 = B1s[0] + s * LDIM; pm.b2 = B2s[0] + s * LDIM;
    pm.gam = Gs[0] + s * LDIM; pm.bet = Be[0] + s * LDIM;
    pm.nRows = EM_N;

    pw.xb = xb;
    pw.W1H = w1h + (size_t)(1 * 6 + s) * 128 * 384;
    pw.W2H = w2h + (size_t)(1 * 6 + s) * 128 * 128;
    pw.W2L = w2l + (size_t)(1 * 6 + s) * 128 * 128;
    pw.b1 = B1s[1] + s * LDIM; pw.b2 = B2s[1] + s * LDIM;
    pw.gam = Gs[1] + s * LDIM; pw.bet = Be[1] + s * LDIM;
    pw.nRows = EW_N;

    if (SORTED) {
      pm.attrIn = msort; pm.attrOut = msort;
      pm.src = psm; pm.dst = pdm;
      pm.oidx = mcsr; pm.origOut = last ? meo : nullptr;
      pw.attrIn = wsort; pw.attrOut = wsort;
      pw.src = psw; pw.dst = pdw;
      pw.oidx = wcsr; pw.origOut = last ? weo : nullptr;
    } else {
      pm.attrIn = mc; pm.attrOut = meo;
      pm.src = mei; pm.dst = mei + EM_N;
      pw.attrIn = wc; pw.attrOut = weo;
      pw.src = wei; pw.dst = wei + EW_N;
    }

    edge_kernel<<<dim3(MB + WB), 256, 0, stream>>>(pm, pw, MB);

    pn.xb = xb; pn.attrIn = xc; pn.attrOut = xo; pn.xbOut = xb;
    pn.off1 = moff; pn.off2 = woff;
    pn.W1H = w1h + (size_t)(2 * 6 + s) * 128 * 384;
    pn.W2H = w2h + (size_t)(2 * 6 + s) * 128 * 128;
    pn.W2L = w2l + (size_t)(2 * 6 + s) * 128 * 128;
    pn.b1 = B1s[2] + s * LDIM; pn.b2 = B2s[2] + s * LDIM;
    pn.gam = Gs[2] + s * LDIM; pn.bet = Be[2] + s * LDIM;
    pn.nRows = NNODE;

    if (SORTED) {
      pn.gsrc1 = msort; pn.gsrc2 = wsort;
      node_kernel<true><<<dim3(NB), 256, 0, stream>>>(pn);
    } else {
      pn.gsrc1 = meo; pn.gsrc2 = weo;
      pn.csr1 = mcsr; pn.csr2 = wcsr;
      node_kernel<false><<<dim3(NB), 256, 0, stream>>>(pn);
    }

    mc = meo; wc = weo; xc = xo;
  }
}